// Round 2
// baseline (2261.646 us; speedup 1.0000x reference)
//
#include <hip/hip_runtime.h>
#include <hip/hip_bf16.h>

#define T_ 1024
#define DM 512
#define HD 256
#define NHEADS 64
#define NB 2

typedef short bf16x8 __attribute__((ext_vector_type(8)));
typedef float f32x4 __attribute__((ext_vector_type(4)));

__device__ __forceinline__ unsigned short f2bf(float f) {
  union { float f; unsigned int i; } w; w.f = f;
  unsigned int x = w.i;
  return (unsigned short)((x + 0x7FFFu + ((x >> 16) & 1u)) >> 16);
}

// ---------------- convert x to bf16 ----------------
__global__ void k_cvt_x(const float* __restrict__ x, unsigned short* __restrict__ xb) {
  int i = blockIdx.x * 256 + threadIdx.x;
  xb[i] = f2bf(x[i]);
}

// ------------- transpose f32 [R][C] -> bf16 [C][R], per-matrix in z -------------
__global__ void k_transpose(const float* __restrict__ in, unsigned short* __restrict__ out,
                            int R, int C) {
  __shared__ float tile[32][33];
  size_t off = (size_t)blockIdx.z * R * C;
  const float* ip = in + off;
  unsigned short* op = out + off;
  int r0 = blockIdx.y * 32, c0 = blockIdx.x * 32;
  int tx = threadIdx.x, ty = threadIdx.y;  // block (32,8)
#pragma unroll
  for (int dy = 0; dy < 32; dy += 8)
    tile[ty + dy][tx] = ip[(size_t)(r0 + ty + dy) * C + c0 + tx];
  __syncthreads();
#pragma unroll
  for (int dy = 0; dy < 32; dy += 8)
    op[(size_t)(c0 + ty + dy) * R + r0 + tx] = f2bf(tile[tx][ty + dy]);
}

// ---------------- K / V projection ----------------
// MODE 1 = K (rope, store [bh][t][d]), MODE 2 = V (no rope, store [bh][d][t])
template <int MODE>
__global__ __launch_bounds__(256) void k_qkv(
    const unsigned short* __restrict__ xb,   // [B][T][DM] bf16
    const unsigned short* __restrict__ wT,   // [NH][HD][DM] bf16 (W transposed)
    const float* __restrict__ cosx, const float* __restrict__ sinx,
    const float* __restrict__ cosy, const float* __restrict__ siny,
    unsigned short* __restrict__ out) {
  const int wave = threadIdx.x >> 6, lane = threadIdx.x & 63;
  const int lo = lane & 15, hi = lane >> 4;
  const int bh = blockIdx.z, b = bh >> 6, h = bh & 63;
  const int t0 = blockIdx.x * 64 + wave * 16;
  const int d0 = blockIdx.y * 128;
  const unsigned short* A = xb + (size_t)b * T_ * DM;
  const unsigned short* Bm = wT + (size_t)h * HD * DM;

  f32x4 acc[8];
#pragma unroll
  for (int i = 0; i < 8; i++) acc[i] = (f32x4)0.0f;

  for (int ck = 0; ck < DM; ck += 32) {
    bf16x8 af = *(const bf16x8*)(A + (size_t)(t0 + lo) * DM + ck + hi * 8);
#pragma unroll
    for (int nt = 0; nt < 8; nt++) {
      bf16x8 bf = *(const bf16x8*)(Bm + (size_t)(d0 + nt * 16 + lo) * DM + ck + hi * 8);
      acc[nt] = __builtin_amdgcn_mfma_f32_16x16x32_bf16(af, bf, acc[nt], 0, 0, 0);
    }
  }

  if (MODE == 2) {
    // store VT[bh][d][t]; lane holds 4 consecutive t
#pragma unroll
    for (int nt = 0; nt < 8; nt++) {
      int d = d0 + nt * 16 + lo;
      unsigned int p0 = (unsigned int)f2bf(acc[nt][0]) | ((unsigned int)f2bf(acc[nt][1]) << 16);
      unsigned int p1 = (unsigned int)f2bf(acc[nt][2]) | ((unsigned int)f2bf(acc[nt][3]) << 16);
      unsigned short* dst = out + (size_t)bh * HD * T_ + (size_t)d * T_ + t0 + hi * 4;
      *(uint2*)dst = make_uint2(p0, p1);
    }
  } else {
    const float* Ct = (d0 == 0) ? cosx : cosy;
    const float* St = (d0 == 0) ? sinx : siny;
#pragma unroll
    for (int nt = 0; nt < 8; nt++) {
      int d = d0 + nt * 16 + lo;
      int fi = (d & 127) >> 1;
#pragma unroll
      for (int j = 0; j < 4; j++) {
        int t = t0 + hi * 4 + j;
        float self = acc[nt][j];
        float other = __shfl_xor(self, 1);
        float c = Ct[t * 64 + fi], s = St[t * 64 + fi];
        float v = (d & 1) ? (other * s + self * c) : (self * c - other * s);
        out[(size_t)bh * T_ * HD + (size_t)t * HD + d] = f2bf(v);
      }
    }
  }
}

// ---------------- fused Q-proj + RoPE + flash attention ----------------
// grid (T/64, B*NH), 4 waves x 16 q-rows
__global__ __launch_bounds__(256) void k_attn_fq(
    const unsigned short* __restrict__ xb,   // [B][T][DM]
    const unsigned short* __restrict__ wqT,  // [NH][HD][DM]
    const unsigned short* __restrict__ k,    // [BH][T][HD]
    const unsigned short* __restrict__ vt,   // [BH][HD][T]
    const float* __restrict__ cosx, const float* __restrict__ sinx,
    const float* __restrict__ cosy, const float* __restrict__ siny,
    unsigned short* __restrict__ attout) {   // [B*T][NH*HD]
  __shared__ __align__(16) unsigned short qlds[4][16][264];  // padded: conflict-free b128
  __shared__ __align__(16) unsigned short plds[4][16][32];
  const int wave = threadIdx.x >> 6, lane = threadIdx.x & 63;
  const int lo = lane & 15, hi = lane >> 4;
  const int bh = blockIdx.y, b = bh >> 6, h = bh & 63;
  const int t0 = blockIdx.x * 64 + wave * 16;

  // ---- phase Q: compute 16 q-rows x 256, RoPE, stash in LDS ----
  {
    const unsigned short* A = xb + (size_t)b * T_ * DM;
    const unsigned short* Bm = wqT + (size_t)h * HD * DM;
    f32x4 qacc[16];
#pragma unroll
    for (int i = 0; i < 16; i++) qacc[i] = (f32x4)0.0f;
    for (int ck = 0; ck < DM; ck += 32) {
      bf16x8 af = *(const bf16x8*)(A + (size_t)(t0 + lo) * DM + ck + hi * 8);
#pragma unroll
      for (int nt = 0; nt < 16; nt++) {
        bf16x8 bf = *(const bf16x8*)(Bm + (size_t)(nt * 16 + lo) * DM + ck + hi * 8);
        qacc[nt] = __builtin_amdgcn_mfma_f32_16x16x32_bf16(af, bf, qacc[nt], 0, 0, 0);
      }
    }
#pragma unroll
    for (int nt = 0; nt < 16; nt++) {
      int d = nt * 16 + lo;
      int fi = (d & 127) >> 1;
      const float* Ct = (nt < 8) ? cosx : cosy;
      const float* St = (nt < 8) ? sinx : siny;
#pragma unroll
      for (int j = 0; j < 4; j++) {
        int t = t0 + hi * 4 + j;
        float self = qacc[nt][j];
        float other = __shfl_xor(self, 1);
        float c = Ct[t * 64 + fi], s = St[t * 64 + fi];
        float v = (d & 1) ? (other * s + self * c) : (self * c - other * s);
        qlds[wave][hi * 4 + j][d] = f2bf(v);
      }
    }
  }

  // ---- load Q A-fragments from LDS ----
  bf16x8 qf[8];
#pragma unroll
  for (int kk = 0; kk < 8; kk++)
    qf[kk] = *(const bf16x8*)(&qlds[wave][lo][kk * 32 + hi * 8]);

  const unsigned short* kp = k + (size_t)bh * T_ * HD;
  const unsigned short* vp = vt + (size_t)bh * HD * T_;

  f32x4 acco[16];
#pragma unroll
  for (int i = 0; i < 16; i++) acco[i] = (f32x4)0.0f;
  float mrun[4] = {-1e30f, -1e30f, -1e30f, -1e30f};
  float lrun[4] = {0.f, 0.f, 0.f, 0.f};
  const float scale = 0.04419417382415922f;  // 1/sqrt(512)

  for (int s0 = 0; s0 < T_; s0 += 32) {
    f32x4 sa0 = (f32x4)0.0f, sa1 = (f32x4)0.0f;
#pragma unroll
    for (int kk = 0; kk < 8; kk++) {
      bf16x8 kf0 = *(const bf16x8*)(kp + (size_t)(s0 + lo) * HD + kk * 32 + hi * 8);
      bf16x8 kf1 = *(const bf16x8*)(kp + (size_t)(s0 + 16 + lo) * HD + kk * 32 + hi * 8);
      sa0 = __builtin_amdgcn_mfma_f32_16x16x32_bf16(qf[kk], kf0, sa0, 0, 0, 0);
      sa1 = __builtin_amdgcn_mfma_f32_16x16x32_bf16(qf[kk], kf1, sa1, 0, 0, 0);
    }
    float mnew[4];
#pragma unroll
    for (int j = 0; j < 4; j++) {
      float v0 = sa0[j] * scale, v1 = sa1[j] * scale;
      sa0[j] = v0; sa1[j] = v1;
      float m = fmaxf(v0, v1);
#pragma unroll
      for (int msk = 1; msk < 16; msk <<= 1)
        m = fmaxf(m, __shfl_xor(m, msk));
      mnew[j] = fmaxf(mrun[j], m);
    }
    bool need = (mnew[0] > mrun[0]) || (mnew[1] > mrun[1]) ||
                (mnew[2] > mrun[2]) || (mnew[3] > mrun[3]);
    if (__any(need)) {
#pragma unroll
      for (int j = 0; j < 4; j++) {
        float f = __expf(mrun[j] - mnew[j]);
        lrun[j] *= f;
#pragma unroll
        for (int nt = 0; nt < 16; nt++) acco[nt][j] *= f;
        mrun[j] = mnew[j];
      }
    }
#pragma unroll
    for (int j = 0; j < 4; j++) {
      float p0 = __expf(sa0[j] - mrun[j]);
      float p1 = __expf(sa1[j] - mrun[j]);
      plds[wave][hi * 4 + j][lo] = f2bf(p0);
      plds[wave][hi * 4 + j][lo + 16] = f2bf(p1);
      float rs = p0 + p1;
#pragma unroll
      for (int msk = 1; msk < 16; msk <<= 1)
        rs += __shfl_xor(rs, msk);
      lrun[j] += rs;
    }
    bf16x8 pa = *(const bf16x8*)(&plds[wave][lo][hi * 8]);
#pragma unroll
    for (int nt = 0; nt < 16; nt++) {
      bf16x8 vf = *(const bf16x8*)(vp + (size_t)(nt * 16 + lo) * T_ + s0 + hi * 8);
      acco[nt] = __builtin_amdgcn_mfma_f32_16x16x32_bf16(pa, vf, acco[nt], 0, 0, 0);
    }
  }

#pragma unroll
  for (int j = 0; j < 4; j++) {
    float inv = 1.0f / lrun[j];
    int t = t0 + hi * 4 + j;
    unsigned short* dst = attout + (size_t)(b * T_ + t) * (NHEADS * HD) + h * HD;
#pragma unroll
    for (int nt = 0; nt < 16; nt++)
      dst[nt * 16 + lo] = f2bf(acco[nt][j] * inv);
  }
}

// ---------------- output projection [2048][16384] @ [16384][512] + bias ----------------
__global__ __launch_bounds__(256) void k_proj(
    const unsigned short* __restrict__ attout,  // [2048][16384]
    const unsigned short* __restrict__ wpT,     // [512][16384]
    const float* __restrict__ bp,               // [512]
    float* __restrict__ out) {                  // [2048][512]
  const int wave = threadIdx.x >> 6, lane = threadIdx.x & 63;
  const int lo = lane & 15, hi = lane >> 4;
  const int t0 = blockIdx.x * 64 + wave * 16;
  const int n0 = blockIdx.y * 64;
  const int K = NHEADS * HD;
  f32x4 acc[4];
#pragma unroll
  for (int i = 0; i < 4; i++) acc[i] = (f32x4)0.0f;
  for (int kk = 0; kk < K; kk += 32) {
    bf16x8 af = *(const bf16x8*)(attout + (size_t)(t0 + lo) * K + kk + hi * 8);
#pragma unroll
    for (int nt = 0; nt < 4; nt++) {
      bf16x8 bf = *(const bf16x8*)(wpT + (size_t)(n0 + nt * 16 + lo) * K + kk + hi * 8);
      acc[nt] = __builtin_amdgcn_mfma_f32_16x16x32_bf16(af, bf, acc[nt], 0, 0, 0);
    }
  }
#pragma unroll
  for (int nt = 0; nt < 4; nt++) {
    int n = n0 + nt * 16 + lo;
    float bias = bp[n];
#pragma unroll
    for (int j = 0; j < 4; j++) {
      int t = t0 + hi * 4 + j;
      out[(size_t)t * DM + n] = acc[nt][j] + bias;
    }
  }
}

extern "C" void kernel_launch(void* const* d_in, const int* in_sizes, int n_in,
                              void* d_out, int out_size, void* d_ws, size_t ws_size,
                              hipStream_t stream) {
  const float* x = (const float*)d_in[0];
  const float* Wq = (const float*)d_in[1];
  const float* Wk = (const float*)d_in[2];
  const float* Wv = (const float*)d_in[3];
  const float* Wp = (const float*)d_in[4];
  const float* bp = (const float*)d_in[5];
  const float* cosx = (const float*)d_in[6];
  const float* sinx = (const float*)d_in[7];
  const float* cosy = (const float*)d_in[8];
  const float* siny = (const float*)d_in[9];
  float* out = (float*)d_out;

  // Workspace plan (peak 210 MB), phase-aliased:
  //   [0,2)    xb
  //   [2,18)   wqT                     (live through attention)
  //   [18,82)  kb      -> phase3: wpT  (kb dead after attention)
  //   [82,146) vtb
  //   [146,210) phase1: wkT[146,162)+wvT[162,178) -> phase2+: ao[146,210)
  const size_t MB = 1ull << 20;
  char* ws = (char*)d_ws;
  unsigned short* xb  = (unsigned short*)(ws + 0 * MB);
  unsigned short* wqT = (unsigned short*)(ws + 2 * MB);
  unsigned short* kb  = (unsigned short*)(ws + 18 * MB);
  unsigned short* vtb = (unsigned short*)(ws + 82 * MB);
  unsigned short* wkT = (unsigned short*)(ws + 146 * MB);
  unsigned short* wvT = (unsigned short*)(ws + 162 * MB);
  unsigned short* ao  = (unsigned short*)(ws + 146 * MB);  // aliases wkT/wvT (dead)
  unsigned short* wpT = (unsigned short*)(ws + 18 * MB);   // aliases kb (dead)

  k_cvt_x<<<(NB * T_ * DM) / 256, 256, 0, stream>>>(x, xb);

  dim3 tb(32, 8);
  k_transpose<<<dim3(HD / 32, DM / 32, NHEADS), tb, 0, stream>>>(Wq, wqT, DM, HD);
  k_transpose<<<dim3(HD / 32, DM / 32, NHEADS), tb, 0, stream>>>(Wk, wkT, DM, HD);
  k_transpose<<<dim3(HD / 32, DM / 32, NHEADS), tb, 0, stream>>>(Wv, wvT, DM, HD);

  dim3 gq(T_ / 64, 2, NB * NHEADS);
  k_qkv<1><<<gq, 256, 0, stream>>>(xb, wkT, cosx, sinx, cosy, siny, kb);
  k_qkv<2><<<gq, 256, 0, stream>>>(xb, wvT, cosx, sinx, cosy, siny, vtb);

  k_attn_fq<<<dim3(T_ / 64, NB * NHEADS), 256, 0, stream>>>(
      xb, wqT, kb, vtb, cosx, sinx, cosy, siny, ao);

  // Wp transpose AFTER attention: wpT aliases the now-dead kb region.
  k_transpose<<<dim3(DM / 32, (NHEADS * HD) / 32, 1), tb, 0, stream>>>(Wp, wpT, NHEADS * HD, DM);

  k_proj<<<dim3((NB * T_) / 64, DM / 64), 256, 0, stream>>>(ao, wpT, bp, out);
}

// Round 4
// 1743.440 us; speedup vs baseline: 1.2972x; 1.2972x over previous
//
#include <hip/hip_runtime.h>
#include <hip/hip_bf16.h>

#define T_ 1024
#define DM 512
#define HD 256
#define NHEADS 64
#define NB 2
#define KVB 32
#define NT (T_ / KVB)

typedef short bf16x8 __attribute__((ext_vector_type(8)));
typedef float f32x4 __attribute__((ext_vector_type(4)));

__device__ __forceinline__ unsigned short f2bf(float f) {
  union { float f; unsigned int i; } w; w.f = f;
  unsigned int x = w.i;
  return (unsigned short)((x + 0x7FFFu + ((x >> 16) & 1u)) >> 16);
}

__device__ __forceinline__ void g2l16(const unsigned short* g, unsigned short* l) {
  __builtin_amdgcn_global_load_lds(
      (const __attribute__((address_space(1))) unsigned int*)g,
      (__attribute__((address_space(3))) unsigned int*)l, 16, 0, 0);
}

// ---------------- convert x to bf16 ----------------
__global__ void k_cvt_x(const float* __restrict__ x, unsigned short* __restrict__ xb) {
  int i = blockIdx.x * 256 + threadIdx.x;
  xb[i] = f2bf(x[i]);
}

// ------------- transpose f32 [R][C] -> bf16 [C][R], per-matrix in z -------------
__global__ void k_transpose(const float* __restrict__ in, unsigned short* __restrict__ out,
                            int R, int C) {
  __shared__ float tile[32][33];
  size_t off = (size_t)blockIdx.z * R * C;
  const float* ip = in + off;
  unsigned short* op = out + off;
  int r0 = blockIdx.y * 32, c0 = blockIdx.x * 32;
  int tx = threadIdx.x, ty = threadIdx.y;  // block (32,8)
#pragma unroll
  for (int dy = 0; dy < 32; dy += 8)
    tile[ty + dy][tx] = ip[(size_t)(r0 + ty + dy) * C + c0 + tx];
  __syncthreads();
#pragma unroll
  for (int dy = 0; dy < 32; dy += 8)
    op[(size_t)(c0 + ty + dy) * R + r0 + tx] = f2bf(tile[tx][ty + dy]);
}

// ---------------- K / V projection ----------------
// MODE 1 = K (rope, store [bh][t][d]), MODE 2 = V (no rope, store [bh][d][t])
template <int MODE>
__global__ __launch_bounds__(256) void k_qkv(
    const unsigned short* __restrict__ xb,   // [B][T][DM] bf16
    const unsigned short* __restrict__ wT,   // [NH][HD][DM] bf16 (W transposed)
    const float* __restrict__ cosx, const float* __restrict__ sinx,
    const float* __restrict__ cosy, const float* __restrict__ siny,
    unsigned short* __restrict__ out) {
  const int wave = threadIdx.x >> 6, lane = threadIdx.x & 63;
  const int lo = lane & 15, hi = lane >> 4;
  // XCD swizzle: all 32 blocks of one head -> one XCD. grid (16,2,128).
  int f = blockIdx.x + 16 * (blockIdx.y + 2 * blockIdx.z);
  int xcd = f & 7, slot = f >> 3;           // slot 0..511
  int bh = ((slot & 15) << 3) | xcd;        // 0..127
  int r2 = slot >> 4;                       // 0..31
  const int b = bh >> 6, h = bh & 63;
  const int t0 = (r2 & 15) * 64 + wave * 16;
  const int d0 = (r2 >> 4) * 128;
  const unsigned short* A = xb + (size_t)b * T_ * DM;
  const unsigned short* Bm = wT + (size_t)h * HD * DM;

  f32x4 acc[8];
#pragma unroll
  for (int i = 0; i < 8; i++) acc[i] = (f32x4)0.0f;

  for (int ck = 0; ck < DM; ck += 32) {
    bf16x8 af = *(const bf16x8*)(A + (size_t)(t0 + lo) * DM + ck + hi * 8);
#pragma unroll
    for (int nt = 0; nt < 8; nt++) {
      bf16x8 bf = *(const bf16x8*)(Bm + (size_t)(d0 + nt * 16 + lo) * DM + ck + hi * 8);
      acc[nt] = __builtin_amdgcn_mfma_f32_16x16x32_bf16(af, bf, acc[nt], 0, 0, 0);
    }
  }

  if (MODE == 2) {
#pragma unroll
    for (int nt = 0; nt < 8; nt++) {
      int d = d0 + nt * 16 + lo;
      unsigned int p0 = (unsigned int)f2bf(acc[nt][0]) | ((unsigned int)f2bf(acc[nt][1]) << 16);
      unsigned int p1 = (unsigned int)f2bf(acc[nt][2]) | ((unsigned int)f2bf(acc[nt][3]) << 16);
      unsigned short* dst = out + (size_t)bh * HD * T_ + (size_t)d * T_ + t0 + hi * 4;
      *(uint2*)dst = make_uint2(p0, p1);
    }
  } else {
    const float* Ct = (d0 == 0) ? cosx : cosy;
    const float* St = (d0 == 0) ? sinx : siny;
#pragma unroll
    for (int nt = 0; nt < 8; nt++) {
      int d = d0 + nt * 16 + lo;
      int fi = (d & 127) >> 1;
#pragma unroll
      for (int j = 0; j < 4; j++) {
        int t = t0 + hi * 4 + j;
        float self = acc[nt][j];
        float other = __shfl_xor(self, 1);
        float c = Ct[t * 64 + fi], s = St[t * 64 + fi];
        float v = (d & 1) ? (other * s + self * c) : (self * c - other * s);
        out[(size_t)bh * T_ * HD + (size_t)t * HD + d] = f2bf(v);
      }
    }
  }
}

// ---------------- fused Q-proj + RoPE + flash attention ----------------
// grid (16, 128); 4 waves x 16 q-rows; K/V LDS-staged, double-buffered.
__global__ __launch_bounds__(256) void k_attn_fq(
    const unsigned short* __restrict__ xb,   // [B][T][DM]
    const unsigned short* __restrict__ wqT,  // [NH][HD][DM]
    const unsigned short* __restrict__ k,    // [BH][T][HD]
    const unsigned short* __restrict__ vt,   // [BH][HD][T]
    const float* __restrict__ cosx, const float* __restrict__ sinx,
    const float* __restrict__ cosy, const float* __restrict__ siny,
    unsigned short* __restrict__ attout) {   // [B*T][NH*HD]
  // LDS: kbuf[2]:16KB@0  vbuf[2]:16KB@32K  plds:5KB@64K ; qlds(33KB) overlays kbuf
  __shared__ __align__(16) unsigned short smem[35328];
  const int wave = threadIdx.x >> 6, lane = threadIdx.x & 63;
  const int lo = lane & 15, hi = lane >> 4;
  // XCD swizzle: all 16 q-blocks of one head -> one XCD. grid (16,128).
  int f = blockIdx.x + (blockIdx.y << 4);
  int xcd = f & 7, slot = f >> 3;
  int bh = ((slot & 15) << 3) | xcd;   // 0..127
  int qb = slot >> 4;                  // 0..15
  const int b = bh >> 6, h = bh & 63;
  const int t0 = qb * 64 + wave * 16;

  unsigned short* qlds = smem;            // [4][16][264] (Q phase only)
  unsigned short* kbuf = smem;            // [2][8192]
  unsigned short* vbuf = smem + 16384;    // [2][8192]
  unsigned short* plds = smem + 32768;    // [4][16][40]

  // ---- phase Q: 16 q-rows x 256, RoPE, stash in LDS ----
  {
    const unsigned short* A = xb + (size_t)b * T_ * DM;
    const unsigned short* Bm = wqT + (size_t)h * HD * DM;
    f32x4 qacc[16];
#pragma unroll
    for (int i = 0; i < 16; i++) qacc[i] = (f32x4)0.0f;
    for (int ck = 0; ck < DM; ck += 32) {
      bf16x8 af = *(const bf16x8*)(A + (size_t)(t0 + lo) * DM + ck + hi * 8);
#pragma unroll
      for (int nt = 0; nt < 16; nt++) {
        bf16x8 bf = *(const bf16x8*)(Bm + (size_t)(nt * 16 + lo) * DM + ck + hi * 8);
        qacc[nt] = __builtin_amdgcn_mfma_f32_16x16x32_bf16(af, bf, qacc[nt], 0, 0, 0);
      }
    }
#pragma unroll
    for (int nt = 0; nt < 16; nt++) {
      int d = nt * 16 + lo;
      int fi = (d & 127) >> 1;
      const float* Ct = (nt < 8) ? cosx : cosy;
      const float* St = (nt < 8) ? sinx : siny;
#pragma unroll
      for (int j = 0; j < 4; j++) {
        int t = t0 + hi * 4 + j;
        float self = qacc[nt][j];
        float other = __shfl_xor(self, 1);
        float c = Ct[t * 64 + fi], s = St[t * 64 + fi];
        float v = (d & 1) ? (other * s + self * c) : (self * c - other * s);
        qlds[(wave * 16 + hi * 4 + j) * 264 + d] = f2bf(v);
      }
    }
  }
  // qlds write/read is same-wave (lgkmcnt-ordered); load Q A-frags to regs
  bf16x8 qf[8];
#pragma unroll
  for (int kk = 0; kk < 8; kk++)
    qf[kk] = *(const bf16x8*)(qlds + (wave * 16 + lo) * 264 + kk * 32 + hi * 8);
  __syncthreads();  // all waves done with qlds before staging overwrites it

  const unsigned short* kp = k + (size_t)bh * T_ * HD;
  const unsigned short* vp = vt + (size_t)bh * HD * T_;

  // STAGE(s0, buf): linear LDS dest, inverse-XOR-swizzled global source.
  // K tile [32 rows][256 d] bf16: granule g (16B); swizzle g^=(row&7) within row.
  // V tile [256 d][32 t] bf16:    granule g (16B); swizzle g^=((d>>1)&3) within row.
#define STAGE(s0, bsel) do {                                                   \
    unsigned short* kdst = kbuf + (bsel) * 8192;                               \
    unsigned short* vdst = vbuf + (bsel) * 8192;                               \
    _Pragma("unroll")                                                          \
    for (int r = 0; r < 4; ++r) {                                              \
      int bc = (r * 4 + wave) * 64;                                            \
      int ck_ = bc + lane;                                                     \
      int row = ck_ >> 5, cid = ck_ & 31;                                      \
      g2l16(kp + (size_t)((s0) + row) * HD + ((cid ^ (row & 7)) << 3),         \
            kdst + bc * 8);                                                    \
      int d_ = ck_ >> 2, cv = ck_ & 3;                                         \
      g2l16(vp + (size_t)d_ * T_ + (s0) + ((cv ^ ((d_ >> 1) & 3)) << 3),       \
            vdst + bc * 8);                                                    \
    }                                                                          \
  } while (0)

  STAGE(0, 0);

  f32x4 acco[16];
#pragma unroll
  for (int i = 0; i < 16; i++) acco[i] = (f32x4)0.0f;
  float mrun[4] = {-1e30f, -1e30f, -1e30f, -1e30f};
  float lrun[4] = {0.f, 0.f, 0.f, 0.f};
  const float scale = 0.04419417382415922f;  // 1/sqrt(512)

  __syncthreads();  // drains vmcnt(0): tile 0 resident

  for (int t = 0; t < NT; ++t) {
    const int cur = t & 1;
    if (t + 1 < NT) STAGE((t + 1) * KVB, 1 - cur);  // async prefetch next tile
    const unsigned short* kc = kbuf + cur * 8192;
    const unsigned short* vc = vbuf + cur * 8192;

    f32x4 sa0 = (f32x4)0.0f, sa1 = (f32x4)0.0f;
#pragma unroll
    for (int kk = 0; kk < 8; kk++) {
      int gc = (kk * 4 + hi) ^ (lo & 7);
      bf16x8 kf0 = *(const bf16x8*)(kc + (lo * 32 + gc) * 8);
      bf16x8 kf1 = *(const bf16x8*)(kc + ((16 + lo) * 32 + gc) * 8);
      sa0 = __builtin_amdgcn_mfma_f32_16x16x32_bf16(qf[kk], kf0, sa0, 0, 0, 0);
      sa1 = __builtin_amdgcn_mfma_f32_16x16x32_bf16(qf[kk], kf1, sa1, 0, 0, 0);
    }
    float mnew[4];
#pragma unroll
    for (int j = 0; j < 4; j++) {
      float v0 = sa0[j] * scale, v1 = sa1[j] * scale;
      sa0[j] = v0; sa1[j] = v1;
      float m = fmaxf(v0, v1);
#pragma unroll
      for (int msk = 1; msk < 16; msk <<= 1)
        m = fmaxf(m, __shfl_xor(m, msk));
      mnew[j] = fmaxf(mrun[j], m);
    }
    bool need = (mnew[0] > mrun[0]) || (mnew[1] > mrun[1]) ||
                (mnew[2] > mrun[2]) || (mnew[3] > mrun[3]);
    if (__any(need)) {
#pragma unroll
      for (int j = 0; j < 4; j++) {
        float fct = __expf(mrun[j] - mnew[j]);
        lrun[j] *= fct;
#pragma unroll
        for (int nt = 0; nt < 16; nt++) acco[nt][j] *= fct;
        mrun[j] = mnew[j];
      }
    }
#pragma unroll
    for (int j = 0; j < 4; j++) {
      float p0 = __expf(sa0[j] - mrun[j]);
      float p1 = __expf(sa1[j] - mrun[j]);
      plds[(wave * 16 + hi * 4 + j) * 40 + lo] = f2bf(p0);
      plds[(wave * 16 + hi * 4 + j) * 40 + lo + 16] = f2bf(p1);
      float rs = p0 + p1;
#pragma unroll
      for (int msk = 1; msk < 16; msk <<= 1)
        rs += __shfl_xor(rs, msk);
      lrun[j] += rs;
    }
    bf16x8 pa = *(const bf16x8*)(plds + (wave * 16 + lo) * 40 + hi * 8);
#pragma unroll
    for (int nt = 0; nt < 16; nt++) {
      int gv = hi ^ ((lo >> 1) & 3);
      bf16x8 vf = *(const bf16x8*)(vc + ((nt * 16 + lo) * 4 + gv) * 8);
      acco[nt] = __builtin_amdgcn_mfma_f32_16x16x32_bf16(pa, vf, acco[nt], 0, 0, 0);
    }
    __syncthreads();  // drains vmcnt (tile t+1 staged) + protects buffer swap
  }
#undef STAGE

#pragma unroll
  for (int j = 0; j < 4; j++) {
    float inv = 1.0f / lrun[j];
    int t = t0 + hi * 4 + j;
    unsigned short* dst = attout + (size_t)(b * T_ + t) * (NHEADS * HD) + h * HD;
#pragma unroll
    for (int nt = 0; nt < 16; nt++)
      dst[nt * 16 + lo] = f2bf(acco[nt][j] * inv);
  }
}

// ---------------- output projection [2048][16384] @ [16384][512] + bias ----------------
__global__ __launch_bounds__(256) void k_proj(
    const unsigned short* __restrict__ attout,  // [2048][16384]
    const unsigned short* __restrict__ wpT,     // [512][16384]
    const float* __restrict__ bp,               // [512]
    float* __restrict__ out) {                  // [2048][512]
  const int wave = threadIdx.x >> 6, lane = threadIdx.x & 63;
  const int lo = lane & 15, hi = lane >> 4;
  // XCD swizzle: all 32 blocks sharing one wpT slice -> one XCD. grid (32,8).
  int f = blockIdx.x + (blockIdx.y << 5);
  int xcd = f & 7, slot = f >> 3;  // slot 0..31
  const int t0 = slot * 64 + wave * 16;
  const int n0 = xcd * 64;
  const int K = NHEADS * HD;
  f32x4 acc[4];
#pragma unroll
  for (int i = 0; i < 4; i++) acc[i] = (f32x4)0.0f;
  for (int kk = 0; kk < K; kk += 32) {
    bf16x8 af = *(const bf16x8*)(attout + (size_t)(t0 + lo) * K + kk + hi * 8);
#pragma unroll
    for (int nt = 0; nt < 4; nt++) {
      bf16x8 bf = *(const bf16x8*)(wpT + (size_t)(n0 + nt * 16 + lo) * K + kk + hi * 8);
      acc[nt] = __builtin_amdgcn_mfma_f32_16x16x32_bf16(af, bf, acc[nt], 0, 0, 0);
    }
  }
#pragma unroll
  for (int nt = 0; nt < 4; nt++) {
    int n = n0 + nt * 16 + lo;
    float bias = bp[n];
#pragma unroll
    for (int j = 0; j < 4; j++) {
      int t = t0 + hi * 4 + j;
      out[(size_t)t * DM + n] = acc[nt][j] + bias;
    }
  }
}

extern "C" void kernel_launch(void* const* d_in, const int* in_sizes, int n_in,
                              void* d_out, int out_size, void* d_ws, size_t ws_size,
                              hipStream_t stream) {
  const float* x = (const float*)d_in[0];
  const float* Wq = (const float*)d_in[1];
  const float* Wk = (const float*)d_in[2];
  const float* Wv = (const float*)d_in[3];
  const float* Wp = (const float*)d_in[4];
  const float* bp = (const float*)d_in[5];
  const float* cosx = (const float*)d_in[6];
  const float* sinx = (const float*)d_in[7];
  const float* cosy = (const float*)d_in[8];
  const float* siny = (const float*)d_in[9];
  float* out = (float*)d_out;

  // Workspace plan (peak 210 MB), phase-aliased.
  const size_t MB = 1ull << 20;
  char* ws = (char*)d_ws;
  unsigned short* xb  = (unsigned short*)(ws + 0 * MB);
  unsigned short* wqT = (unsigned short*)(ws + 2 * MB);
  unsigned short* kb  = (unsigned short*)(ws + 18 * MB);
  unsigned short* vtb = (unsigned short*)(ws + 82 * MB);
  unsigned short* wkT = (unsigned short*)(ws + 146 * MB);
  unsigned short* wvT = (unsigned short*)(ws + 162 * MB);
  unsigned short* ao  = (unsigned short*)(ws + 146 * MB);  // aliases wkT/wvT (dead)
  unsigned short* wpT = (unsigned short*)(ws + 18 * MB);   // aliases kb (dead)

  k_cvt_x<<<(NB * T_ * DM) / 256, 256, 0, stream>>>(x, xb);

  dim3 tb(32, 8);
  k_transpose<<<dim3(HD / 32, DM / 32, NHEADS), tb, 0, stream>>>(Wq, wqT, DM, HD);
  k_transpose<<<dim3(HD / 32, DM / 32, NHEADS), tb, 0, stream>>>(Wk, wkT, DM, HD);
  k_transpose<<<dim3(HD / 32, DM / 32, NHEADS), tb, 0, stream>>>(Wv, wvT, DM, HD);

  dim3 gq(T_ / 64, 2, NB * NHEADS);
  k_qkv<1><<<gq, 256, 0, stream>>>(xb, wkT, cosx, sinx, cosy, siny, kb);
  k_qkv<2><<<gq, 256, 0, stream>>>(xb, wvT, cosx, sinx, cosy, siny, vtb);

  k_attn_fq<<<dim3(T_ / 64, NB * NHEADS), 256, 0, stream>>>(
      xb, wqT, kb, vtb, cosx, sinx, cosy, siny, ao);

  k_transpose<<<dim3(DM / 32, (NHEADS * HD) / 32, 1), tb, 0, stream>>>(Wp, wpT, NHEADS * HD, DM);

  k_proj<<<dim3((NB * T_) / 64, DM / 64), 256, 0, stream>>>(ao, wpT, bp, out);
}

// Round 6
// 1571.562 us; speedup vs baseline: 1.4391x; 1.1094x over previous
//
#include <hip/hip_runtime.h>
#include <hip/hip_bf16.h>

#define T_ 1024
#define DM 512
#define HD 256
#define NHEADS 64
#define NB 2
#define KVB 32
#define NT (T_ / KVB)

typedef short bf16x8 __attribute__((ext_vector_type(8)));
typedef float f32x4 __attribute__((ext_vector_type(4)));

__device__ __forceinline__ unsigned short f2bf(float f) {
  union { float f; unsigned int i; } w; w.f = f;
  unsigned int x = w.i;
  return (unsigned short)((x + 0x7FFFu + ((x >> 16) & 1u)) >> 16);
}

__device__ __forceinline__ void g2l16(const unsigned short* g, unsigned short* l) {
  __builtin_amdgcn_global_load_lds(
      (const __attribute__((address_space(1))) unsigned int*)g,
      (__attribute__((address_space(3))) unsigned int*)l, 16, 0, 0);
}

// ---------------- convert x to bf16 ----------------
__global__ void k_cvt_x(const float* __restrict__ x, unsigned short* __restrict__ xb) {
  int i = blockIdx.x * 256 + threadIdx.x;
  xb[i] = f2bf(x[i]);
}

// ------------- transpose f32 [R][C] -> bf16 [C][R], per-matrix in z -------------
__global__ void k_transpose(const float* __restrict__ in, unsigned short* __restrict__ out,
                            int R, int C) {
  __shared__ float tile[32][33];
  size_t off = (size_t)blockIdx.z * R * C;
  const float* ip = in + off;
  unsigned short* op = out + off;
  int r0 = blockIdx.y * 32, c0 = blockIdx.x * 32;
  int tx = threadIdx.x, ty = threadIdx.y;  // block (32,8)
#pragma unroll
  for (int dy = 0; dy < 32; dy += 8)
    tile[ty + dy][tx] = ip[(size_t)(r0 + ty + dy) * C + c0 + tx];
  __syncthreads();
#pragma unroll
  for (int dy = 0; dy < 32; dy += 8)
    op[(size_t)(c0 + ty + dy) * R + r0 + tx] = f2bf(tile[tx][ty + dy]);
}

// ---------------- fused K + V projection ----------------
// K: rope, store [bh][t][d]; V: no rope, store transposed [bh][d][t]
__global__ __launch_bounds__(256) void k_kv(
    const unsigned short* __restrict__ xb,   // [B][T][DM] bf16
    const unsigned short* __restrict__ wkT,  // [NH][HD][DM]
    const unsigned short* __restrict__ wvT,  // [NH][HD][DM]
    const float* __restrict__ cosx, const float* __restrict__ sinx,
    const float* __restrict__ cosy, const float* __restrict__ siny,
    unsigned short* __restrict__ kout,       // [BH][T][HD]
    unsigned short* __restrict__ vout) {     // [BH][HD][T]
  const int wave = threadIdx.x >> 6, lane = threadIdx.x & 63;
  const int lo = lane & 15, hi = lane >> 4;
  // XCD swizzle, work-unit fast within head: grid (16,2,128)
  int f = blockIdx.x + 16 * blockIdx.y + 32 * blockIdx.z;
  int xcd = f & 7, slot = f >> 3;        // slot 0..511
  int r2 = slot & 31, hgrp = slot >> 5;  // r2: 16 t-chunks x 2 d-halves
  int bh = (hgrp << 3) | xcd;            // 0..127
  const int b = bh >> 6, h = bh & 63;
  const int t0 = (r2 & 15) * 64 + wave * 16;
  const int d0 = (r2 >> 4) * 128;
  const unsigned short* A = xb + (size_t)b * T_ * DM;
  const unsigned short* Bk = wkT + (size_t)h * HD * DM;
  const unsigned short* Bv = wvT + (size_t)h * HD * DM;

  f32x4 ak[8], av[8];
#pragma unroll
  for (int i = 0; i < 8; i++) { ak[i] = (f32x4)0.0f; av[i] = (f32x4)0.0f; }

  for (int ck = 0; ck < DM; ck += 32) {
    bf16x8 af = *(const bf16x8*)(A + (size_t)(t0 + lo) * DM + ck + hi * 8);
#pragma unroll
    for (int nt = 0; nt < 8; nt++) {
      bf16x8 bk = *(const bf16x8*)(Bk + (size_t)(d0 + nt * 16 + lo) * DM + ck + hi * 8);
      ak[nt] = __builtin_amdgcn_mfma_f32_16x16x32_bf16(af, bk, ak[nt], 0, 0, 0);
      bf16x8 bv = *(const bf16x8*)(Bv + (size_t)(d0 + nt * 16 + lo) * DM + ck + hi * 8);
      av[nt] = __builtin_amdgcn_mfma_f32_16x16x32_bf16(af, bv, av[nt], 0, 0, 0);
    }
  }

  // K epilogue: RoPE + store [bh][t][d]
  {
    const float* Ct = (d0 == 0) ? cosx : cosy;
    const float* St = (d0 == 0) ? sinx : siny;
#pragma unroll
    for (int nt = 0; nt < 8; nt++) {
      int d = d0 + nt * 16 + lo;
      int fi = (d & 127) >> 1;
#pragma unroll
      for (int j = 0; j < 4; j++) {
        int t = t0 + hi * 4 + j;
        float self = ak[nt][j];
        float other = __shfl_xor(self, 1);
        float c = Ct[t * 64 + fi], s = St[t * 64 + fi];
        float v = (d & 1) ? (other * s + self * c) : (self * c - other * s);
        kout[(size_t)bh * T_ * HD + (size_t)t * HD + d] = f2bf(v);
      }
    }
  }
  // V epilogue: store transposed [bh][d][t]
#pragma unroll
  for (int nt = 0; nt < 8; nt++) {
    int d = d0 + nt * 16 + lo;
    unsigned int p0 = (unsigned int)f2bf(av[nt][0]) | ((unsigned int)f2bf(av[nt][1]) << 16);
    unsigned int p1 = (unsigned int)f2bf(av[nt][2]) | ((unsigned int)f2bf(av[nt][3]) << 16);
    unsigned short* dst = vout + (size_t)bh * HD * T_ + (size_t)d * T_ + t0 + hi * 4;
    *(uint2*)dst = make_uint2(p0, p1);
  }
}

// ---------------- fused Q-proj + RoPE + flash attention ----------------
// grid (8, 128); 8 waves x 16 q-rows = 128 q-rows per block.
// K/V double-buffered in LDS via global_load_lds; counted-vmcnt pipeline.
__global__ __launch_bounds__(512) void k_attn_fq(
    const unsigned short* __restrict__ xb,   // [B][T][DM]
    const unsigned short* __restrict__ wqT,  // [NH][HD][DM]
    const unsigned short* __restrict__ k,    // [BH][T][HD]
    const unsigned short* __restrict__ vt,   // [BH][HD][T]
    const float* __restrict__ cosx, const float* __restrict__ sinx,
    const float* __restrict__ cosy, const float* __restrict__ siny,
    unsigned short* __restrict__ attout) {   // [B*T][NH*HD]
  // LDS (shorts): kbuf[2][8192]@0, vbuf[2][8192]@16384, plds[8][16][40]@32768.
  // qlds [8][16][264] (Q phase only) overlays the whole region.
  __shared__ __align__(16) unsigned short smem[37888];  // 75776 B
  const int wave = threadIdx.x >> 6, lane = threadIdx.x & 63;
  const int lo = lane & 15, hi = lane >> 4;
  // XCD swizzle, q-block fast within head: grid (8,128) -> f 0..1023
  int f = blockIdx.x + (blockIdx.y << 3);
  int xcd = f & 7, slot = f >> 3;     // 0..127
  int qb = slot & 7, hgrp = slot >> 3;
  int bh = (hgrp << 3) | xcd;         // 0..127
  const int b = bh >> 6, h = bh & 63;
  const int t0 = qb * 128 + wave * 16;

  unsigned short* qlds = smem;            // [8][16][264]
  unsigned short* kbuf = smem;            // [2][8192]
  unsigned short* vbuf = smem + 16384;    // [2][8192]
  unsigned short* plds = smem + 32768;    // [8][16][40]

  // ---- phase Q: 16 q-rows x 256 per wave, RoPE, stash in LDS ----
  {
    const unsigned short* A = xb + (size_t)b * T_ * DM;
    const unsigned short* Bm = wqT + (size_t)h * HD * DM;
    f32x4 qacc[16];
#pragma unroll
    for (int i = 0; i < 16; i++) qacc[i] = (f32x4)0.0f;
    for (int ck = 0; ck < DM; ck += 32) {
      bf16x8 af = *(const bf16x8*)(A + (size_t)(t0 + lo) * DM + ck + hi * 8);
#pragma unroll
      for (int nt = 0; nt < 16; nt++) {
        bf16x8 bf = *(const bf16x8*)(Bm + (size_t)(nt * 16 + lo) * DM + ck + hi * 8);
        qacc[nt] = __builtin_amdgcn_mfma_f32_16x16x32_bf16(af, bf, qacc[nt], 0, 0, 0);
      }
    }
#pragma unroll
    for (int nt = 0; nt < 16; nt++) {
      int d = nt * 16 + lo;
      int fi = (d & 127) >> 1;
      const float* Ct = (nt < 8) ? cosx : cosy;
      const float* St = (nt < 8) ? sinx : siny;
#pragma unroll
      for (int j = 0; j < 4; j++) {
        int t = t0 + hi * 4 + j;
        float self = qacc[nt][j];
        float other = __shfl_xor(self, 1);
        float c = Ct[t * 64 + fi], s = St[t * 64 + fi];
        float v = (d & 1) ? (other * s + self * c) : (self * c - other * s);
        qlds[(wave * 16 + hi * 4 + j) * 264 + d] = f2bf(v);
      }
    }
  }
  // qlds write/read is same-wave; load Q A-frags to regs
  bf16x8 qf[8];
#pragma unroll
  for (int kk = 0; kk < 8; kk++)
    qf[kk] = *(const bf16x8*)(qlds + (wave * 16 + lo) * 264 + kk * 32 + hi * 8);
  __syncthreads();  // all waves done with qlds before staging overwrites it

  const unsigned short* kp = k + (size_t)bh * T_ * HD;
  const unsigned short* vp = vt + (size_t)bh * HD * T_;

  // STAGE(s0, buf): linear LDS dest, inverse-XOR-swizzled global source.
  // K tile [32 rows][256 d]: granule g=(row,cid); holds d-granule cid^(row&7).
  // V tile [256 d][32 t]:    granule g=(d,cv);   holds t-granule cv^((d>>1)&3).
  // 4 g2l16 per wave per tile.
#define STAGE(s0, bsel) do {                                                   \
    unsigned short* kdst = kbuf + (bsel) * 8192;                               \
    unsigned short* vdst = vbuf + (bsel) * 8192;                               \
    _Pragma("unroll")                                                          \
    for (int r = 0; r < 2; ++r) {                                              \
      int base = r * 512 + wave * 64;                                          \
      int ck_ = base + lane;                                                   \
      int row = ck_ >> 5, cid = ck_ & 31;                                      \
      g2l16(kp + (size_t)((s0) + row) * HD + ((cid ^ (row & 7)) << 3),         \
            kdst + base * 8);                                                  \
      int d_ = ck_ >> 2, cv = ck_ & 3;                                         \
      g2l16(vp + (size_t)d_ * T_ + (s0) + ((cv ^ ((d_ >> 1) & 3)) << 3),       \
            vdst + base * 8);                                                  \
    }                                                                          \
  } while (0)

  STAGE(0, 0);

  f32x4 acco[16];
#pragma unroll
  for (int i = 0; i < 16; i++) acco[i] = (f32x4)0.0f;
  float mrun[4] = {-1e30f, -1e30f, -1e30f, -1e30f};
  float lrun[4] = {0.f, 0.f, 0.f, 0.f};
  const float scale = 0.04419417382415922f;  // 1/sqrt(512)

  for (int t = 0; t < NT; ++t) {
    const int cur = t & 1;
    // barrier 1: all waves finished reading buf[1-cur] (compute t-1)
    asm volatile("s_waitcnt lgkmcnt(0)" ::: "memory");
    __builtin_amdgcn_sched_barrier(0);
    __builtin_amdgcn_s_barrier();
    __builtin_amdgcn_sched_barrier(0);
    if (t + 1 < NT) {
      STAGE((t + 1) * KVB, 1 - cur);                      // prefetch t+1
      asm volatile("s_waitcnt vmcnt(4)" ::: "memory");    // tile t landed; t+1 in flight
    } else {
      asm volatile("s_waitcnt vmcnt(0)" ::: "memory");
    }
    __builtin_amdgcn_sched_barrier(0);
    __builtin_amdgcn_s_barrier();  // barrier 2: all waves' tile-t loads visible
    __builtin_amdgcn_sched_barrier(0);

    const unsigned short* kc = kbuf + cur * 8192;
    const unsigned short* vc = vbuf + cur * 8192;

    f32x4 sa0 = (f32x4)0.0f, sa1 = (f32x4)0.0f;
    __builtin_amdgcn_s_setprio(1);
#pragma unroll
    for (int kk = 0; kk < 8; kk++) {
      int gc = (kk * 4 + hi) ^ (lo & 7);
      bf16x8 kf0 = *(const bf16x8*)(kc + (lo * 32 + gc) * 8);
      bf16x8 kf1 = *(const bf16x8*)(kc + ((16 + lo) * 32 + gc) * 8);
      sa0 = __builtin_amdgcn_mfma_f32_16x16x32_bf16(qf[kk], kf0, sa0, 0, 0, 0);
      sa1 = __builtin_amdgcn_mfma_f32_16x16x32_bf16(qf[kk], kf1, sa1, 0, 0, 0);
    }
    __builtin_amdgcn_s_setprio(0);
    float mnew[4];
#pragma unroll
    for (int j = 0; j < 4; j++) {
      float v0 = sa0[j] * scale, v1 = sa1[j] * scale;
      sa0[j] = v0; sa1[j] = v1;
      float m = fmaxf(v0, v1);
#pragma unroll
      for (int msk = 1; msk < 16; msk <<= 1)
        m = fmaxf(m, __shfl_xor(m, msk));
      mnew[j] = fmaxf(mrun[j], m);
    }
    bool need = (mnew[0] > mrun[0]) || (mnew[1] > mrun[1]) ||
                (mnew[2] > mrun[2]) || (mnew[3] > mrun[3]);
    if (__any(need)) {
#pragma unroll
      for (int j = 0; j < 4; j++) {
        float fct = __expf(mrun[j] - mnew[j]);
        lrun[j] *= fct;
#pragma unroll
        for (int nt = 0; nt < 16; nt++) acco[nt][j] *= fct;
        mrun[j] = mnew[j];
      }
    }
#pragma unroll
    for (int j = 0; j < 4; j++) {
      float p0 = __expf(sa0[j] - mrun[j]);
      float p1 = __expf(sa1[j] - mrun[j]);
      plds[(wave * 16 + hi * 4 + j) * 40 + lo] = f2bf(p0);
      plds[(wave * 16 + hi * 4 + j) * 40 + lo + 16] = f2bf(p1);
      float rs = p0 + p1;
#pragma unroll
      for (int msk = 1; msk < 16; msk <<= 1)
        rs += __shfl_xor(rs, msk);
      lrun[j] += rs;
    }
    bf16x8 pa = *(const bf16x8*)(plds + (wave * 16 + lo) * 40 + hi * 8);
    __builtin_amdgcn_s_setprio(1);
#pragma unroll
    for (int nt = 0; nt < 16; nt++) {
      int gv = hi ^ ((lo >> 1) & 3);
      bf16x8 vf = *(const bf16x8*)(vc + ((nt * 16 + lo) * 4 + gv) * 8);
      acco[nt] = __builtin_amdgcn_mfma_f32_16x16x32_bf16(pa, vf, acco[nt], 0, 0, 0);
    }
    __builtin_amdgcn_s_setprio(0);
  }
#undef STAGE

#pragma unroll
  for (int j = 0; j < 4; j++) {
    float inv = 1.0f / lrun[j];
    int t = t0 + hi * 4 + j;
    unsigned short* dst = attout + (size_t)(b * T_ + t) * (NHEADS * HD) + h * HD;
#pragma unroll
    for (int nt = 0; nt < 16; nt++)
      dst[nt * 16 + lo] = f2bf(acco[nt][j] * inv);
  }
}

// ---------------- output projection [2048][16384] @ [16384][512] + bias ----------------
__global__ __launch_bounds__(256) void k_proj(
    const unsigned short* __restrict__ attout,  // [2048][16384]
    const unsigned short* __restrict__ wpT,     // [512][16384]
    const float* __restrict__ bp,               // [512]
    float* __restrict__ out) {                  // [2048][512]
  const int wave = threadIdx.x >> 6, lane = threadIdx.x & 63;
  const int lo = lane & 15, hi = lane >> 4;
  // XCD swizzle: all 32 blocks sharing one wpT slice -> one XCD. grid (32,8).
  int f = blockIdx.x + (blockIdx.y << 5);
  int xcd = f & 7, slot = f >> 3;  // slot 0..31
  const int t0 = slot * 64 + wave * 16;
  const int n0 = xcd * 64;
  const int K = NHEADS * HD;
  f32x4 acc[4];
#pragma unroll
  for (int i = 0; i < 4; i++) acc[i] = (f32x4)0.0f;
  for (int kk = 0; kk < K; kk += 32) {
    bf16x8 af = *(const bf16x8*)(attout + (size_t)(t0 + lo) * K + kk + hi * 8);
#pragma unroll
    for (int nt = 0; nt < 4; nt++) {
      bf16x8 bf = *(const bf16x8*)(wpT + (size_t)(n0 + nt * 16 + lo) * K + kk + hi * 8);
      acc[nt] = __builtin_amdgcn_mfma_f32_16x16x32_bf16(af, bf, acc[nt], 0, 0, 0);
    }
  }
#pragma unroll
  for (int nt = 0; nt < 4; nt++) {
    int n = n0 + nt * 16 + lo;
    float bias = bp[n];
#pragma unroll
    for (int j = 0; j < 4; j++) {
      int t = t0 + hi * 4 + j;
      out[(size_t)t * DM + n] = acc[nt][j] + bias;
    }
  }
}

extern "C" void kernel_launch(void* const* d_in, const int* in_sizes, int n_in,
                              void* d_out, int out_size, void* d_ws, size_t ws_size,
                              hipStream_t stream) {
  const float* x = (const float*)d_in[0];
  const float* Wq = (const float*)d_in[1];
  const float* Wk = (const float*)d_in[2];
  const float* Wv = (const float*)d_in[3];
  const float* Wp = (const float*)d_in[4];
  const float* bp = (const float*)d_in[5];
  const float* cosx = (const float*)d_in[6];
  const float* sinx = (const float*)d_in[7];
  const float* cosy = (const float*)d_in[8];
  const float* siny = (const float*)d_in[9];
  float* out = (float*)d_out;

  // Workspace plan (peak 210 MB), phase-aliased.
  const size_t MB = 1ull << 20;
  char* ws = (char*)d_ws;
  unsigned short* xb  = (unsigned short*)(ws + 0 * MB);
  unsigned short* wqT = (unsigned short*)(ws + 2 * MB);
  unsigned short* kb  = (unsigned short*)(ws + 18 * MB);
  unsigned short* vtb = (unsigned short*)(ws + 82 * MB);
  unsigned short* wkT = (unsigned short*)(ws + 146 * MB);
  unsigned short* wvT = (unsigned short*)(ws + 162 * MB);
  unsigned short* ao  = (unsigned short*)(ws + 146 * MB);  // aliases wkT/wvT (dead)
  unsigned short* wpT = (unsigned short*)(ws + 18 * MB);   // aliases kb (dead)

  k_cvt_x<<<(NB * T_ * DM) / 256, 256, 0, stream>>>(x, xb);

  dim3 tb(32, 8);
  k_transpose<<<dim3(HD / 32, DM / 32, NHEADS), tb, 0, stream>>>(Wq, wqT, DM, HD);
  k_transpose<<<dim3(HD / 32, DM / 32, NHEADS), tb, 0, stream>>>(Wk, wkT, DM, HD);
  k_transpose<<<dim3(HD / 32, DM / 32, NHEADS), tb, 0, stream>>>(Wv, wvT, DM, HD);

  k_kv<<<dim3(16, 2, NB * NHEADS), 256, 0, stream>>>(
      xb, wkT, wvT, cosx, sinx, cosy, siny, kb, vtb);

  k_attn_fq<<<dim3(T_ / 128, NB * NHEADS), 512, 0, stream>>>(
      xb, wqT, kb, vtb, cosx, sinx, cosy, siny, ao);

  k_transpose<<<dim3(DM / 32, (NHEADS * HD) / 32, 1), tb, 0, stream>>>(Wp, wpT, NHEADS * HD, DM);

  k_proj<<<dim3((NB * T_) / 64, DM / 64), 256, 0, stream>>>(ao, wpT, bp, out);
}

// Round 7
// 1562.380 us; speedup vs baseline: 1.4476x; 1.0059x over previous
//
#include <hip/hip_runtime.h>
#include <hip/hip_bf16.h>

#define T_ 1024
#define DM 512
#define HD 256
#define NHEADS 64
#define NB 2
#define KVB 32
#define NT (T_ / KVB)

typedef short bf16x8 __attribute__((ext_vector_type(8)));
typedef float f32x4 __attribute__((ext_vector_type(4)));

__device__ __forceinline__ unsigned short f2bf(float f) {
  union { float f; unsigned int i; } w; w.f = f;
  unsigned int x = w.i;
  return (unsigned short)((x + 0x7FFFu + ((x >> 16) & 1u)) >> 16);
}

__device__ __forceinline__ unsigned pk2(float x, float y) {
  return (unsigned)f2bf(x) | ((unsigned)f2bf(y) << 16);
}

__device__ __forceinline__ void g2l16(const unsigned short* g, unsigned short* l) {
  __builtin_amdgcn_global_load_lds(
      (const __attribute__((address_space(1))) unsigned int*)g,
      (__attribute__((address_space(3))) unsigned int*)l, 16, 0, 0);
}

// ---------------- convert x to bf16 ----------------
__global__ void k_cvt_x(const float* __restrict__ x, unsigned short* __restrict__ xb) {
  int i = blockIdx.x * 256 + threadIdx.x;
  xb[i] = f2bf(x[i]);
}

// ------------- transpose f32 [R][C] -> bf16 [C][R], per-matrix in z -------------
__global__ void k_transpose(const float* __restrict__ in, unsigned short* __restrict__ out,
                            int R, int C) {
  __shared__ float tile[32][33];
  size_t off = (size_t)blockIdx.z * R * C;
  const float* ip = in + off;
  unsigned short* op = out + off;
  int r0 = blockIdx.y * 32, c0 = blockIdx.x * 32;
  int tx = threadIdx.x, ty = threadIdx.y;  // block (32,8)
#pragma unroll
  for (int dy = 0; dy < 32; dy += 8)
    tile[ty + dy][tx] = ip[(size_t)(r0 + ty + dy) * C + c0 + tx];
  __syncthreads();
#pragma unroll
  for (int dy = 0; dy < 32; dy += 8)
    op[(size_t)(c0 + ty + dy) * R + r0 + tx] = f2bf(tile[tx][ty + dy]);
}

// ---------------- fused K + V projection ----------------
__global__ __launch_bounds__(256) void k_kv(
    const unsigned short* __restrict__ xb,   // [B][T][DM] bf16
    const unsigned short* __restrict__ wkT,  // [NH][HD][DM]
    const unsigned short* __restrict__ wvT,  // [NH][HD][DM]
    const float* __restrict__ cosx, const float* __restrict__ sinx,
    const float* __restrict__ cosy, const float* __restrict__ siny,
    unsigned short* __restrict__ kout,       // [BH][T][HD]
    unsigned short* __restrict__ vout) {     // [BH][HD][T]
  const int wave = threadIdx.x >> 6, lane = threadIdx.x & 63;
  const int lo = lane & 15, hi = lane >> 4;
  int f = blockIdx.x + 16 * blockIdx.y + 32 * blockIdx.z;
  int xcd = f & 7, slot = f >> 3;        // slot 0..511
  int r2 = slot & 31, hgrp = slot >> 5;  // r2: 16 t-chunks x 2 d-halves
  int bh = (hgrp << 3) | xcd;            // 0..127
  const int b = bh >> 6, h = bh & 63;
  const int t0 = (r2 & 15) * 64 + wave * 16;
  const int d0 = (r2 >> 4) * 128;
  const unsigned short* A = xb + (size_t)b * T_ * DM;
  const unsigned short* Bk = wkT + (size_t)h * HD * DM;
  const unsigned short* Bv = wvT + (size_t)h * HD * DM;

  f32x4 ak[8], av[8];
#pragma unroll
  for (int i = 0; i < 8; i++) { ak[i] = (f32x4)0.0f; av[i] = (f32x4)0.0f; }

  for (int ck = 0; ck < DM; ck += 32) {
    bf16x8 af = *(const bf16x8*)(A + (size_t)(t0 + lo) * DM + ck + hi * 8);
#pragma unroll
    for (int nt = 0; nt < 8; nt++) {
      bf16x8 bk = *(const bf16x8*)(Bk + (size_t)(d0 + nt * 16 + lo) * DM + ck + hi * 8);
      ak[nt] = __builtin_amdgcn_mfma_f32_16x16x32_bf16(af, bk, ak[nt], 0, 0, 0);
      bf16x8 bv = *(const bf16x8*)(Bv + (size_t)(d0 + nt * 16 + lo) * DM + ck + hi * 8);
      av[nt] = __builtin_amdgcn_mfma_f32_16x16x32_bf16(af, bv, av[nt], 0, 0, 0);
    }
  }

  {
    const float* Ct = (d0 == 0) ? cosx : cosy;
    const float* St = (d0 == 0) ? sinx : siny;
#pragma unroll
    for (int nt = 0; nt < 8; nt++) {
      int d = d0 + nt * 16 + lo;
      int fi = (d & 127) >> 1;
#pragma unroll
      for (int j = 0; j < 4; j++) {
        int t = t0 + hi * 4 + j;
        float self = ak[nt][j];
        float other = __shfl_xor(self, 1);
        float c = Ct[t * 64 + fi], s = St[t * 64 + fi];
        float v = (d & 1) ? (other * s + self * c) : (self * c - other * s);
        kout[(size_t)bh * T_ * HD + (size_t)t * HD + d] = f2bf(v);
      }
    }
  }
#pragma unroll
  for (int nt = 0; nt < 8; nt++) {
    int d = d0 + nt * 16 + lo;
    unsigned int p0 = (unsigned int)f2bf(av[nt][0]) | ((unsigned int)f2bf(av[nt][1]) << 16);
    unsigned int p1 = (unsigned int)f2bf(av[nt][2]) | ((unsigned int)f2bf(av[nt][3]) << 16);
    unsigned short* dst = vout + (size_t)bh * HD * T_ + (size_t)d * T_ + t0 + hi * 4;
    *(uint2*)dst = make_uint2(p0, p1);
  }
}

// ---------------- fused Q-proj + RoPE + flash attention (swapped QK^T) ----------------
// grid (8, 128); 8 waves x 16 q-rows = 128 q-rows per block.
// S^T = mfma(K,Q): lane holds q=lo, 8 s-values -> in-lane softmax.
// O^T = mfma(V^T,P): P delivered via 8 lane-exchange shfls. No plds.
__global__ __launch_bounds__(512) void k_attn_fq(
    const unsigned short* __restrict__ xb,   // [B][T][DM]
    const unsigned short* __restrict__ wqT,  // [NH][HD][DM]
    const unsigned short* __restrict__ k,    // [BH][T][HD]
    const unsigned short* __restrict__ vt,   // [BH][HD][T]
    const float* __restrict__ cosx, const float* __restrict__ sinx,
    const float* __restrict__ cosy, const float* __restrict__ siny,
    unsigned short* __restrict__ attout) {   // [B*T][NH*HD]
  // LDS (shorts): kbuf[2][8192]@0, vbuf[2][8192]@16384 (64KB);
  // qlds [8][16][264] (Q phase only) overlays everything (67584 B total).
  __shared__ __align__(16) unsigned short smem[33792];
  const int wave = threadIdx.x >> 6, lane = threadIdx.x & 63;
  const int lo = lane & 15, hi = lane >> 4;
  int f = blockIdx.x + (blockIdx.y << 3);
  int xcd = f & 7, slot = f >> 3;     // 0..127
  int qb = slot & 7, hgrp = slot >> 3;
  int bh = (hgrp << 3) | xcd;         // 0..127
  const int b = bh >> 6, h = bh & 63;
  const int t0 = qb * 128 + wave * 16;

  unsigned short* qlds = smem;            // [8][16][264]
  unsigned short* kbuf = smem;            // [2][8192]
  unsigned short* vbuf = smem + 16384;    // [2][8192]

  // ---- phase Q: 16 q-rows x 256 per wave, RoPE, stash in LDS ----
  {
    const unsigned short* A = xb + (size_t)b * T_ * DM;
    const unsigned short* Bm = wqT + (size_t)h * HD * DM;
    f32x4 qacc[16];
#pragma unroll
    for (int i = 0; i < 16; i++) qacc[i] = (f32x4)0.0f;
    for (int ck = 0; ck < DM; ck += 32) {
      bf16x8 af = *(const bf16x8*)(A + (size_t)(t0 + lo) * DM + ck + hi * 8);
#pragma unroll
      for (int nt = 0; nt < 16; nt++) {
        bf16x8 bf = *(const bf16x8*)(Bm + (size_t)(nt * 16 + lo) * DM + ck + hi * 8);
        qacc[nt] = __builtin_amdgcn_mfma_f32_16x16x32_bf16(af, bf, qacc[nt], 0, 0, 0);
      }
    }
#pragma unroll
    for (int nt = 0; nt < 16; nt++) {
      int d = nt * 16 + lo;
      int fi = (d & 127) >> 1;
      const float* Ct = (nt < 8) ? cosx : cosy;
      const float* St = (nt < 8) ? sinx : siny;
#pragma unroll
      for (int j = 0; j < 4; j++) {
        int t = t0 + hi * 4 + j;
        float self = qacc[nt][j];
        float other = __shfl_xor(self, 1);
        float c = Ct[t * 64 + fi], s = St[t * 64 + fi];
        float v = (d & 1) ? (other * s + self * c) : (self * c - other * s);
        qlds[(wave * 16 + hi * 4 + j) * 264 + d] = f2bf(v);
      }
    }
  }
  // qf = B-frag for swapped QK: lane lo = q-col, k = d.
  bf16x8 qf[8];
#pragma unroll
  for (int kk = 0; kk < 8; kk++)
    qf[kk] = *(const bf16x8*)(qlds + (wave * 16 + lo) * 264 + kk * 32 + hi * 8);
  __syncthreads();  // all waves done with qlds before staging overwrites it

  const unsigned short* kp = k + (size_t)bh * T_ * HD;
  const unsigned short* vp = vt + (size_t)bh * HD * T_;

#define STAGE(s0, bsel) do {                                                   \
    unsigned short* kdst = kbuf + (bsel) * 8192;                               \
    unsigned short* vdst = vbuf + (bsel) * 8192;                               \
    _Pragma("unroll")                                                          \
    for (int r = 0; r < 2; ++r) {                                              \
      int base = r * 512 + wave * 64;                                          \
      int ck_ = base + lane;                                                   \
      int row = ck_ >> 5, cid = ck_ & 31;                                      \
      g2l16(kp + (size_t)((s0) + row) * HD + ((cid ^ (row & 7)) << 3),         \
            kdst + base * 8);                                                  \
      int d_ = ck_ >> 2, cv = ck_ & 3;                                         \
      g2l16(vp + (size_t)d_ * T_ + (s0) + ((cv ^ ((d_ >> 1) & 3)) << 3),       \
            vdst + base * 8);                                                  \
    }                                                                          \
  } while (0)

  STAGE(0, 0);

  f32x4 acco[16];
#pragma unroll
  for (int i = 0; i < 16; i++) acco[i] = (f32x4)0.0f;
  float mrun = -1e30f, lrun = 0.f;
  const float scale = 0.04419417382415922f;  // 1/sqrt(512)
  const int srcA = lo + ((hi & 1) << 5);     // P-exchange source lanes
  const int srcB = srcA + 16;
  const int gv = hi ^ ((lo >> 1) & 3);

  for (int t = 0; t < NT; ++t) {
    const int cur = t & 1;
    asm volatile("s_waitcnt lgkmcnt(0)" ::: "memory");
    __builtin_amdgcn_sched_barrier(0);
    __builtin_amdgcn_s_barrier();
    __builtin_amdgcn_sched_barrier(0);
    if (t + 1 < NT) {
      STAGE((t + 1) * KVB, 1 - cur);
      asm volatile("s_waitcnt vmcnt(4)" ::: "memory");
    } else {
      asm volatile("s_waitcnt vmcnt(0)" ::: "memory");
    }
    __builtin_amdgcn_sched_barrier(0);
    __builtin_amdgcn_s_barrier();
    __builtin_amdgcn_sched_barrier(0);

    const unsigned short* kc = kbuf + cur * 8192;
    const unsigned short* vc = vbuf + cur * 8192;

    // S^T = K·Q^T : lane (lo,hi) -> q=lo, s = hi*4+j (sa0), 16+hi*4+j (sa1)
    f32x4 sa0 = (f32x4)0.0f, sa1 = (f32x4)0.0f;
    __builtin_amdgcn_s_setprio(1);
#pragma unroll
    for (int kk = 0; kk < 8; kk++) {
      int gc = (kk * 4 + hi) ^ (lo & 7);
      bf16x8 kf0 = *(const bf16x8*)(kc + (lo * 32 + gc) * 8);
      bf16x8 kf1 = *(const bf16x8*)(kc + ((16 + lo) * 32 + gc) * 8);
      sa0 = __builtin_amdgcn_mfma_f32_16x16x32_bf16(kf0, qf[kk], sa0, 0, 0, 0);
      sa1 = __builtin_amdgcn_mfma_f32_16x16x32_bf16(kf1, qf[kk], sa1, 0, 0, 0);
    }
    __builtin_amdgcn_s_setprio(0);

    // in-lane softmax over 8 s-values
    float pv[8];
#pragma unroll
    for (int j = 0; j < 4; j++) { pv[j] = sa0[j] * scale; pv[4 + j] = sa1[j] * scale; }
    float pm = pv[0];
#pragma unroll
    for (int i = 1; i < 8; i++) pm = fmaxf(pm, pv[i]);
    pm = fmaxf(pm, __shfl_xor(pm, 16));
    pm = fmaxf(pm, __shfl_xor(pm, 32));
    if (__any(pm > mrun + 8.0f)) {  // defer-max (T13)
      float mnew = fmaxf(mrun, pm);
      float fct = __expf(mrun - mnew);
      lrun *= fct;
#pragma unroll
      for (int nt = 0; nt < 16; nt++)
#pragma unroll
        for (int j = 0; j < 4; j++) acco[nt][j] *= fct;
      mrun = mnew;
    }
    float ps = 0.f;
#pragma unroll
    for (int i = 0; i < 8; i++) { pv[i] = __expf(pv[i] - mrun); ps += pv[i]; }
    ps += __shfl_xor(ps, 16);
    ps += __shfl_xor(ps, 32);
    lrun += ps;

    // pack P->bf16 and exchange to B-frag layout (k=s, col=q)
    unsigned a0 = pk2(pv[0], pv[1]), a1 = pk2(pv[2], pv[3]);
    unsigned b0 = pk2(pv[4], pv[5]), b1 = pk2(pv[6], pv[7]);
    unsigned qa0 = (unsigned)__shfl((int)a0, srcA);
    unsigned qa1 = (unsigned)__shfl((int)a1, srcA);
    unsigned qa2 = (unsigned)__shfl((int)a0, srcB);
    unsigned qa3 = (unsigned)__shfl((int)a1, srcB);
    unsigned qb0 = (unsigned)__shfl((int)b0, srcA);
    unsigned qb1 = (unsigned)__shfl((int)b1, srcA);
    unsigned qb2 = (unsigned)__shfl((int)b0, srcB);
    unsigned qb3 = (unsigned)__shfl((int)b1, srcB);
    bool up = hi >= 2;
    union { unsigned u[4]; bf16x8 v; } pu;
    pu.u[0] = up ? qb0 : qa0;
    pu.u[1] = up ? qb1 : qa1;
    pu.u[2] = up ? qb2 : qa2;
    pu.u[3] = up ? qb3 : qa3;
    bf16x8 pb = pu.v;

    // O^T += V^T · P : lane (lo,hi) -> q=lo, d = nt*16+hi*4+j
    __builtin_amdgcn_s_setprio(1);
#pragma unroll
    for (int nt = 0; nt < 16; nt++) {
      bf16x8 vf = *(const bf16x8*)(vc + ((nt * 16 + lo) * 4 + gv) * 8);
      acco[nt] = __builtin_amdgcn_mfma_f32_16x16x32_bf16(vf, pb, acco[nt], 0, 0, 0);
    }
    __builtin_amdgcn_s_setprio(0);
  }
#undef STAGE

  float inv = 1.0f / lrun;
  int t = t0 + lo;
  unsigned short* dst = attout + (size_t)(b * T_ + t) * (NHEADS * HD) + h * HD;
#pragma unroll
  for (int nt = 0; nt < 16; nt++) {
    unsigned w0 = pk2(acco[nt][0] * inv, acco[nt][1] * inv);
    unsigned w1 = pk2(acco[nt][2] * inv, acco[nt][3] * inv);
    *(uint2*)(dst + nt * 16 + hi * 4) = make_uint2(w0, w1);
  }
}

// ---------------- output projection [2048][16384] @ [16384][512] + bias ----------------
// grid (64,8): 512 blocks, tile 32t x 64n; wave = 16t x 32n.
__global__ __launch_bounds__(256) void k_proj(
    const unsigned short* __restrict__ attout,  // [2048][16384]
    const unsigned short* __restrict__ wpT,     // [512][16384]
    const float* __restrict__ bp,               // [512]
    float* __restrict__ out) {                  // [2048][512]
  const int wave = threadIdx.x >> 6, lane = threadIdx.x & 63;
  const int lo = lane & 15, hi = lane >> 4;
  int f = blockIdx.x + (blockIdx.y << 6);
  int xcd = f & 7, slot = f >> 3;  // slot 0..63
  const int t0 = slot * 32 + (wave & 1) * 16;
  const int n0 = xcd * 64 + (wave >> 1) * 32;
  const int K = NHEADS * HD;
  f32x4 acc[2];
#pragma unroll
  for (int i = 0; i < 2; i++) acc[i] = (f32x4)0.0f;
  for (int kk = 0; kk < K; kk += 32) {
    bf16x8 af = *(const bf16x8*)(attout + (size_t)(t0 + lo) * K + kk + hi * 8);
#pragma unroll
    for (int nt = 0; nt < 2; nt++) {
      bf16x8 bf = *(const bf16x8*)(wpT + (size_t)(n0 + nt * 16 + lo) * K + kk + hi * 8);
      acc[nt] = __builtin_amdgcn_mfma_f32_16x16x32_bf16(af, bf, acc[nt], 0, 0, 0);
    }
  }
#pragma unroll
  for (int nt = 0; nt < 2; nt++) {
    int n = n0 + nt * 16 + lo;
    float bias = bp[n];
#pragma unroll
    for (int j = 0; j < 4; j++) {
      int t = t0 + hi * 4 + j;
      out[(size_t)t * DM + n] = acc[nt][j] + bias;
    }
  }
}

extern "C" void kernel_launch(void* const* d_in, const int* in_sizes, int n_in,
                              void* d_out, int out_size, void* d_ws, size_t ws_size,
                              hipStream_t stream) {
  const float* x = (const float*)d_in[0];
  const float* Wq = (const float*)d_in[1];
  const float* Wk = (const float*)d_in[2];
  const float* Wv = (const float*)d_in[3];
  const float* Wp = (const float*)d_in[4];
  const float* bp = (const float*)d_in[5];
  const float* cosx = (const float*)d_in[6];
  const float* sinx = (const float*)d_in[7];
  const float* cosy = (const float*)d_in[8];
  const float* siny = (const float*)d_in[9];
  float* out = (float*)d_out;

  // Workspace plan (peak 210 MB), phase-aliased.
  const size_t MB = 1ull << 20;
  char* ws = (char*)d_ws;
  unsigned short* xb  = (unsigned short*)(ws + 0 * MB);
  unsigned short* wqT = (unsigned short*)(ws + 2 * MB);
  unsigned short* kb  = (unsigned short*)(ws + 18 * MB);
  unsigned short* vtb = (unsigned short*)(ws + 82 * MB);
  unsigned short* wkT = (unsigned short*)(ws + 146 * MB);
  unsigned short* wvT = (unsigned short*)(ws + 162 * MB);
  unsigned short* ao  = (unsigned short*)(ws + 146 * MB);  // aliases wkT/wvT (dead)
  unsigned short* wpT = (unsigned short*)(ws + 18 * MB);   // aliases kb (dead)

  k_cvt_x<<<(NB * T_ * DM) / 256, 256, 0, stream>>>(x, xb);

  dim3 tb(32, 8);
  k_transpose<<<dim3(HD / 32, DM / 32, NHEADS), tb, 0, stream>>>(Wq, wqT, DM, HD);
  k_transpose<<<dim3(HD / 32, DM / 32, NHEADS), tb, 0, stream>>>(Wk, wkT, DM, HD);
  k_transpose<<<dim3(HD / 32, DM / 32, NHEADS), tb, 0, stream>>>(Wv, wvT, DM, HD);

  k_kv<<<dim3(16, 2, NB * NHEADS), 256, 0, stream>>>(
      xb, wkT, wvT, cosx, sinx, cosy, siny, kb, vtb);

  k_attn_fq<<<dim3(T_ / 128, NB * NHEADS), 512, 0, stream>>>(
      xb, wqT, kb, vtb, cosx, sinx, cosy, siny, ao);

  k_transpose<<<dim3(DM / 32, (NHEADS * HD) / 32, 1), tb, 0, stream>>>(Wp, wpT, NHEADS * HD, DM);

  k_proj<<<dim3(64, 8), 256, 0, stream>>>(ao, wpT, bp, out);
}

// Round 8
// 893.041 us; speedup vs baseline: 2.5325x; 1.7495x over previous
//
#include <hip/hip_runtime.h>
#include <hip/hip_bf16.h>

#define T_ 1024
#define DM 512
#define HD 256
#define NHEADS 64
#define NB 2
#define KVB 32
#define NT (T_ / KVB)

typedef short bf16x8 __attribute__((ext_vector_type(8)));
typedef float f32x4 __attribute__((ext_vector_type(4)));

__device__ __forceinline__ unsigned short f2bf(float f) {
  union { float f; unsigned int i; } w; w.f = f;
  unsigned int x = w.i;
  return (unsigned short)((x + 0x7FFFu + ((x >> 16) & 1u)) >> 16);
}

__device__ __forceinline__ unsigned pk2(float x, float y) {
  return (unsigned)f2bf(x) | ((unsigned)f2bf(y) << 16);
}

__device__ __forceinline__ void g2l16(const unsigned short* g, unsigned short* l) {
  __builtin_amdgcn_global_load_lds(
      (const __attribute__((address_space(1))) unsigned int*)g,
      (__attribute__((address_space(3))) unsigned int*)l, 16, 0, 0);
}

// ---------------- convert x to bf16 ----------------
__global__ void k_cvt_x(const float* __restrict__ x, unsigned short* __restrict__ xb) {
  int i = blockIdx.x * 256 + threadIdx.x;
  xb[i] = f2bf(x[i]);
}

// ------------- transpose f32 [R][C] -> bf16 [C][R], per-matrix in z -------------
__global__ void k_transpose(const float* __restrict__ in, unsigned short* __restrict__ out,
                            int R, int C) {
  __shared__ float tile[32][33];
  size_t off = (size_t)blockIdx.z * R * C;
  const float* ip = in + off;
  unsigned short* op = out + off;
  int r0 = blockIdx.y * 32, c0 = blockIdx.x * 32;
  int tx = threadIdx.x, ty = threadIdx.y;  // block (32,8)
#pragma unroll
  for (int dy = 0; dy < 32; dy += 8)
    tile[ty + dy][tx] = ip[(size_t)(r0 + ty + dy) * C + c0 + tx];
  __syncthreads();
#pragma unroll
  for (int dy = 0; dy < 32; dy += 8)
    op[(size_t)(c0 + ty + dy) * R + r0 + tx] = f2bf(tile[tx][ty + dy]);
}

// ---------------- K+V projection as staged GEMM (m97 2-phase) ----------------
// A = xb [2048][512]; B^T = wkT/wvT as [16384][512]; tile 128x128, BK=32.
// z=0: K (RoPE, store [bh][t][d]); z=1: V (store [bh][d][t]).
__global__ __launch_bounds__(256) void k_kvgemm(
    const unsigned short* __restrict__ xb,
    const unsigned short* __restrict__ wkT,
    const unsigned short* __restrict__ wvT,
    const float* __restrict__ cosx, const float* __restrict__ sinx,
    const float* __restrict__ cosy, const float* __restrict__ siny,
    unsigned short* __restrict__ kout,   // [BH][T][HD]
    unsigned short* __restrict__ vout) { // [BH][HD][T]
  __shared__ __align__(16) unsigned short As[2][128 * 32];
  __shared__ __align__(16) unsigned short Bs[2][128 * 32];
  const int tid = threadIdx.x, wave = tid >> 6, lane = tid & 63;
  const int lo = lane & 15, hi = lane >> 4;
  const int wr = wave >> 1, wc = wave & 1;
  // XCD swizzle: grid (16,128,2) -> per-XCD contiguous n/z slabs, m fast.
  int f = blockIdx.x + 16 * blockIdx.y + 2048 * blockIdx.z;
  int xcd = f & 7, slot = f >> 3;        // slot 0..511
  int mb = slot & 15;
  int nz = (xcd << 5) | (slot >> 4);     // 0..255
  int z = nz & 1, nb = nz >> 1;          // nb 0..127
  const int m0 = mb * 128, n0 = nb * 128;
  const unsigned short* wT = z ? wvT : wkT;

#define STG(ck, bsel) do {                                                  \
    _Pragma("unroll")                                                       \
    for (int r = 0; r < 2; ++r) {                                           \
      int g = r * 256 + tid;                                                \
      int row = g >> 2, kc = g & 3;                                         \
      g2l16(xb + (size_t)(m0 + row) * DM + (ck) + kc * 8,                   \
            &As[bsel][(r * 256 + wave * 64) * 8]);                          \
      g2l16(wT + (size_t)(n0 + row) * DM + (ck) + kc * 8,                   \
            &Bs[bsel][(r * 256 + wave * 64) * 8]);                          \
    }                                                                       \
  } while (0)

  STG(0, 0);
  __syncthreads();

  f32x4 acc[4][4];
#pragma unroll
  for (int i = 0; i < 4; i++)
#pragma unroll
    for (int j = 0; j < 4; j++) acc[i][j] = (f32x4)0.0f;

  for (int t = 0; t < 16; ++t) {
    const int cur = t & 1;
    if (t < 15) STG((t + 1) * 32, cur ^ 1);
    bf16x8 af[4], bf[4];
#pragma unroll
    for (int mi = 0; mi < 4; mi++)
      af[mi] = *(const bf16x8*)(&As[cur][(wr * 64 + mi * 16 + lo) * 32 + hi * 8]);
#pragma unroll
    for (int ni = 0; ni < 4; ni++)
      bf[ni] = *(const bf16x8*)(&Bs[cur][(wc * 64 + ni * 16 + lo) * 32 + hi * 8]);
#pragma unroll
    for (int mi = 0; mi < 4; mi++)
#pragma unroll
      for (int ni = 0; ni < 4; ni++)
        acc[mi][ni] = __builtin_amdgcn_mfma_f32_16x16x32_bf16(af[mi], bf[ni], acc[mi][ni], 0, 0, 0);
    __syncthreads();
  }
#undef STG

  const int hh = n0 >> 8;           // head
  const int dbase = n0 & 255;       // 0 or 128
  const int b = m0 >> 10;           // batch (m0 128-aligned -> uniform)
  const int bh = b * NHEADS + hh;
  const int mloc = m0 & 1023;

  if (z == 0) {
    const float* Ct = (dbase == 0) ? cosx : cosy;
    const float* St = (dbase == 0) ? sinx : siny;
#pragma unroll
    for (int mi = 0; mi < 4; mi++) {
      int tl = mloc + wr * 64 + mi * 16 + hi * 4;
#pragma unroll
      for (int ni = 0; ni < 4; ni++) {
        int d = dbase + wc * 64 + ni * 16 + lo;
        int fi = (d & 127) >> 1;
#pragma unroll
        for (int j = 0; j < 4; j++) {
          int t = tl + j;
          float self = acc[mi][ni][j];
          float other = __shfl_xor(self, 1);
          float c = Ct[t * 64 + fi], s = St[t * 64 + fi];
          float v = (d & 1) ? (other * s + self * c) : (self * c - other * s);
          kout[(size_t)bh * T_ * HD + (size_t)t * HD + d] = f2bf(v);
        }
      }
    }
  } else {
#pragma unroll
    for (int mi = 0; mi < 4; mi++) {
      int tl = mloc + wr * 64 + mi * 16 + hi * 4;
#pragma unroll
      for (int ni = 0; ni < 4; ni++) {
        int d = dbase + wc * 64 + ni * 16 + lo;
        uint2 w;
        w.x = pk2(acc[mi][ni][0], acc[mi][ni][1]);
        w.y = pk2(acc[mi][ni][2], acc[mi][ni][3]);
        *(uint2*)(vout + (size_t)bh * HD * T_ + (size_t)d * T_ + tl) = w;
      }
    }
  }
}

// ---------------- fused Q-proj + RoPE + flash attention (swapped QK^T) ----------------
__global__ __launch_bounds__(512) void k_attn_fq(
    const unsigned short* __restrict__ xb,   // [B][T][DM]
    const unsigned short* __restrict__ wqT,  // [NH][HD][DM]
    const unsigned short* __restrict__ k,    // [BH][T][HD]
    const unsigned short* __restrict__ vt,   // [BH][HD][T]
    const float* __restrict__ cosx, const float* __restrict__ sinx,
    const float* __restrict__ cosy, const float* __restrict__ siny,
    unsigned short* __restrict__ attout) {   // [B*T][NH*HD]
  __shared__ __align__(16) unsigned short smem[33792];
  const int wave = threadIdx.x >> 6, lane = threadIdx.x & 63;
  const int lo = lane & 15, hi = lane >> 4;
  int f = blockIdx.x + (blockIdx.y << 3);
  int xcd = f & 7, slot = f >> 3;     // 0..127
  int qb = slot & 7, hgrp = slot >> 3;
  int bh = (hgrp << 3) | xcd;         // 0..127
  const int b = bh >> 6, h = bh & 63;
  const int t0 = qb * 128 + wave * 16;

  unsigned short* qlds = smem;            // [8][16][264]
  unsigned short* kbuf = smem;            // [2][8192]
  unsigned short* vbuf = smem + 16384;    // [2][8192]

  {
    const unsigned short* A = xb + (size_t)b * T_ * DM;
    const unsigned short* Bm = wqT + (size_t)h * HD * DM;
    f32x4 qacc[16];
#pragma unroll
    for (int i = 0; i < 16; i++) qacc[i] = (f32x4)0.0f;
    for (int ck = 0; ck < DM; ck += 32) {
      bf16x8 af = *(const bf16x8*)(A + (size_t)(t0 + lo) * DM + ck + hi * 8);
#pragma unroll
      for (int nt = 0; nt < 16; nt++) {
        bf16x8 bf = *(const bf16x8*)(Bm + (size_t)(nt * 16 + lo) * DM + ck + hi * 8);
        qacc[nt] = __builtin_amdgcn_mfma_f32_16x16x32_bf16(af, bf, qacc[nt], 0, 0, 0);
      }
    }
#pragma unroll
    for (int nt = 0; nt < 16; nt++) {
      int d = nt * 16 + lo;
      int fi = (d & 127) >> 1;
      const float* Ct = (nt < 8) ? cosx : cosy;
      const float* St = (nt < 8) ? sinx : siny;
#pragma unroll
      for (int j = 0; j < 4; j++) {
        int t = t0 + hi * 4 + j;
        float self = qacc[nt][j];
        float other = __shfl_xor(self, 1);
        float c = Ct[t * 64 + fi], s = St[t * 64 + fi];
        float v = (d & 1) ? (other * s + self * c) : (self * c - other * s);
        qlds[(wave * 16 + hi * 4 + j) * 264 + d] = f2bf(v);
      }
    }
  }
  bf16x8 qf[8];
#pragma unroll
  for (int kk = 0; kk < 8; kk++)
    qf[kk] = *(const bf16x8*)(qlds + (wave * 16 + lo) * 264 + kk * 32 + hi * 8);
  __syncthreads();

  const unsigned short* kp = k + (size_t)bh * T_ * HD;
  const unsigned short* vp = vt + (size_t)bh * HD * T_;

#define STAGE(s0, bsel) do {                                                   \
    unsigned short* kdst = kbuf + (bsel) * 8192;                               \
    unsigned short* vdst = vbuf + (bsel) * 8192;                               \
    _Pragma("unroll")                                                          \
    for (int r = 0; r < 2; ++r) {                                              \
      int base = r * 512 + wave * 64;                                          \
      int ck_ = base + lane;                                                   \
      int row = ck_ >> 5, cid = ck_ & 31;                                      \
      g2l16(kp + (size_t)((s0) + row) * HD + ((cid ^ (row & 7)) << 3),         \
            kdst + base * 8);                                                  \
      int d_ = ck_ >> 2, cv = ck_ & 3;                                         \
      g2l16(vp + (size_t)d_ * T_ + (s0) + ((cv ^ ((d_ >> 1) & 3)) << 3),       \
            vdst + base * 8);                                                  \
    }                                                                          \
  } while (0)

  STAGE(0, 0);

  f32x4 acco[16];
#pragma unroll
  for (int i = 0; i < 16; i++) acco[i] = (f32x4)0.0f;
  float mrun = -1e30f, lrun = 0.f;
  const float scale = 0.04419417382415922f;  // 1/sqrt(512)
  const int srcA = lo + ((hi & 1) << 5);
  const int srcB = srcA + 16;
  const int gv = hi ^ ((lo >> 1) & 3);

  for (int t = 0; t < NT; ++t) {
    const int cur = t & 1;
    asm volatile("s_waitcnt lgkmcnt(0)" ::: "memory");
    __builtin_amdgcn_sched_barrier(0);
    __builtin_amdgcn_s_barrier();
    __builtin_amdgcn_sched_barrier(0);
    if (t + 1 < NT) {
      STAGE((t + 1) * KVB, 1 - cur);
      asm volatile("s_waitcnt vmcnt(4)" ::: "memory");
    } else {
      asm volatile("s_waitcnt vmcnt(0)" ::: "memory");
    }
    __builtin_amdgcn_sched_barrier(0);
    __builtin_amdgcn_s_barrier();
    __builtin_amdgcn_sched_barrier(0);

    const unsigned short* kc = kbuf + cur * 8192;
    const unsigned short* vc = vbuf + cur * 8192;

    f32x4 sa0 = (f32x4)0.0f, sa1 = (f32x4)0.0f;
    __builtin_amdgcn_s_setprio(1);
#pragma unroll
    for (int kk = 0; kk < 8; kk++) {
      int gc = (kk * 4 + hi) ^ (lo & 7);
      bf16x8 kf0 = *(const bf16x8*)(kc + (lo * 32 + gc) * 8);
      bf16x8 kf1 = *(const bf16x8*)(kc + ((16 + lo) * 32 + gc) * 8);
      sa0 = __builtin_amdgcn_mfma_f32_16x16x32_bf16(kf0, qf[kk], sa0, 0, 0, 0);
      sa1 = __builtin_amdgcn_mfma_f32_16x16x32_bf16(kf1, qf[kk], sa1, 0, 0, 0);
    }
    __builtin_amdgcn_s_setprio(0);

    float pv[8];
#pragma unroll
    for (int j = 0; j < 4; j++) { pv[j] = sa0[j] * scale; pv[4 + j] = sa1[j] * scale; }
    float pm = pv[0];
#pragma unroll
    for (int i = 1; i < 8; i++) pm = fmaxf(pm, pv[i]);
    pm = fmaxf(pm, __shfl_xor(pm, 16));
    pm = fmaxf(pm, __shfl_xor(pm, 32));
    if (__any(pm > mrun + 8.0f)) {
      float mnew = fmaxf(mrun, pm);
      float fct = __expf(mrun - mnew);
      lrun *= fct;
#pragma unroll
      for (int nt = 0; nt < 16; nt++)
#pragma unroll
        for (int j = 0; j < 4; j++) acco[nt][j] *= fct;
      mrun = mnew;
    }
    float ps = 0.f;
#pragma unroll
    for (int i = 0; i < 8; i++) { pv[i] = __expf(pv[i] - mrun); ps += pv[i]; }
    ps += __shfl_xor(ps, 16);
    ps += __shfl_xor(ps, 32);
    lrun += ps;

    unsigned a0 = pk2(pv[0], pv[1]), a1 = pk2(pv[2], pv[3]);
    unsigned b0 = pk2(pv[4], pv[5]), b1 = pk2(pv[6], pv[7]);
    unsigned qa0 = (unsigned)__shfl((int)a0, srcA);
    unsigned qa1 = (unsigned)__shfl((int)a1, srcA);
    unsigned qa2 = (unsigned)__shfl((int)a0, srcB);
    unsigned qa3 = (unsigned)__shfl((int)a1, srcB);
    unsigned qb0 = (unsigned)__shfl((int)b0, srcA);
    unsigned qb1 = (unsigned)__shfl((int)b1, srcA);
    unsigned qb2 = (unsigned)__shfl((int)b0, srcB);
    unsigned qb3 = (unsigned)__shfl((int)b1, srcB);
    bool up = hi >= 2;
    union { unsigned u[4]; bf16x8 v; } pu;
    pu.u[0] = up ? qb0 : qa0;
    pu.u[1] = up ? qb1 : qa1;
    pu.u[2] = up ? qb2 : qa2;
    pu.u[3] = up ? qb3 : qa3;
    bf16x8 pb = pu.v;

    __builtin_amdgcn_s_setprio(1);
#pragma unroll
    for (int nt = 0; nt < 16; nt++) {
      bf16x8 vf = *(const bf16x8*)(vc + ((nt * 16 + lo) * 4 + gv) * 8);
      acco[nt] = __builtin_amdgcn_mfma_f32_16x16x32_bf16(vf, pb, acco[nt], 0, 0, 0);
    }
    __builtin_amdgcn_s_setprio(0);
  }
#undef STAGE

  float inv = 1.0f / lrun;
  int t = t0 + lo;
  unsigned short* dst = attout + (size_t)(b * T_ + t) * (NHEADS * HD) + h * HD;
#pragma unroll
  for (int nt = 0; nt < 16; nt++) {
    unsigned w0 = pk2(acco[nt][0] * inv, acco[nt][1] * inv);
    unsigned w1 = pk2(acco[nt][2] * inv, acco[nt][3] * inv);
    *(uint2*)(dst + nt * 16 + hi * 4) = make_uint2(w0, w1);
  }
}

// ---------------- output projection: split-K staged GEMM ----------------
// A = ao [2048][16384]; B^T = wpT [512][16384]; tile 128x128, BK=32, 8-way K-split.
__global__ __launch_bounds__(256) void k_proj_sk(
    const unsigned short* __restrict__ ao,
    const unsigned short* __restrict__ wpT,
    float* __restrict__ pp) {   // [8][2048][512] partials
  __shared__ __align__(16) unsigned short As[2][128 * 32];
  __shared__ __align__(16) unsigned short Bs[2][128 * 32];
  const int tid = threadIdx.x, wave = tid >> 6, lane = tid & 63;
  const int lo = lane & 15, hi = lane >> 4;
  const int wr = wave >> 1, wc = wave & 1;
  const int m0 = blockIdx.x * 128;        // 16 m-tiles
  const int n0 = blockIdx.y * 128;        // 4 n-tiles
  const int kz = blockIdx.z;              // 8 k-chunks of 2048
  const int K = NHEADS * HD;              // 16384
  const int koff = kz * 2048;

#define STGP(ck, bsel) do {                                                 \
    _Pragma("unroll")                                                       \
    for (int r = 0; r < 2; ++r) {                                           \
      int g = r * 256 + tid;                                                \
      int row = g >> 2, kc = g & 3;                                         \
      g2l16(ao + (size_t)(m0 + row) * K + koff + (ck) + kc * 8,             \
            &As[bsel][(r * 256 + wave * 64) * 8]);                          \
      g2l16(wpT + (size_t)(n0 + row) * K + koff + (ck) + kc * 8,            \
            &Bs[bsel][(r * 256 + wave * 64) * 8]);                          \
    }                                                                       \
  } while (0)

  STGP(0, 0);
  __syncthreads();

  f32x4 acc[4][4];
#pragma unroll
  for (int i = 0; i < 4; i++)
#pragma unroll
    for (int j = 0; j < 4; j++) acc[i][j] = (f32x4)0.0f;

  for (int t = 0; t < 64; ++t) {
    const int cur = t & 1;
    if (t < 63) STGP((t + 1) * 32, cur ^ 1);
    bf16x8 af[4], bf[4];
#pragma unroll
    for (int mi = 0; mi < 4; mi++)
      af[mi] = *(const bf16x8*)(&As[cur][(wr * 64 + mi * 16 + lo) * 32 + hi * 8]);
#pragma unroll
    for (int ni = 0; ni < 4; ni++)
      bf[ni] = *(const bf16x8*)(&Bs[cur][(wc * 64 + ni * 16 + lo) * 32 + hi * 8]);
#pragma unroll
    for (int mi = 0; mi < 4; mi++)
#pragma unroll
      for (int ni = 0; ni < 4; ni++)
        acc[mi][ni] = __builtin_amdgcn_mfma_f32_16x16x32_bf16(af[mi], bf[ni], acc[mi][ni], 0, 0, 0);
    __syncthreads();
  }
#undef STGP

  float* base = pp + (size_t)kz * 2048 * 512;
#pragma unroll
  for (int mi = 0; mi < 4; mi++) {
    int tl = m0 + wr * 64 + mi * 16 + hi * 4;
#pragma unroll
    for (int ni = 0; ni < 4; ni++) {
      int n = n0 + wc * 64 + ni * 16 + lo;
#pragma unroll
      for (int j = 0; j < 4; j++)
        base[(size_t)(tl + j) * 512 + n] = acc[mi][ni][j];
    }
  }
}

// ---------------- reduce partials + bias ----------------
__global__ __launch_bounds__(256) void k_pred(
    const float* __restrict__ pp, const float* __restrict__ bp,
    float* __restrict__ out) {
  int idx = (blockIdx.x * 256 + threadIdx.x) * 4;   // 2048*512 / 4 = 262144 threads
  f32x4 s = *(const f32x4*)(bp + (idx & 511));
#pragma unroll
  for (int kz = 0; kz < 8; kz++)
    s += *(const f32x4*)(pp + (size_t)kz * 1048576 + idx);
  *(f32x4*)(out + idx) = s;
}

extern "C" void kernel_launch(void* const* d_in, const int* in_sizes, int n_in,
                              void* d_out, int out_size, void* d_ws, size_t ws_size,
                              hipStream_t stream) {
  const float* x = (const float*)d_in[0];
  const float* Wq = (const float*)d_in[1];
  const float* Wk = (const float*)d_in[2];
  const float* Wv = (const float*)d_in[3];
  const float* Wp = (const float*)d_in[4];
  const float* bp = (const float*)d_in[5];
  const float* cosx = (const float*)d_in[6];
  const float* sinx = (const float*)d_in[7];
  const float* cosy = (const float*)d_in[8];
  const float* siny = (const float*)d_in[9];
  float* out = (float*)d_out;

  // Workspace plan (peak 210 MB), phase-aliased:
  //  [0,2) xb | [2,18) wqT | [18,82) kb  -> post-attn: wpT[18,34) + pp[34,66)
  //  [82,146) vtb | [146,210): wkT[146,162)+wvT[162,178) -> post-kv: ao[146,210)
  const size_t MB = 1ull << 20;
  char* ws = (char*)d_ws;
  unsigned short* xb  = (unsigned short*)(ws + 0 * MB);
  unsigned short* wqT = (unsigned short*)(ws + 2 * MB);
  unsigned short* kb  = (unsigned short*)(ws + 18 * MB);
  unsigned short* vtb = (unsigned short*)(ws + 82 * MB);
  unsigned short* wkT = (unsigned short*)(ws + 146 * MB);
  unsigned short* wvT = (unsigned short*)(ws + 162 * MB);
  unsigned short* ao  = (unsigned short*)(ws + 146 * MB);  // aliases wkT/wvT (dead)
  unsigned short* wpT = (unsigned short*)(ws + 18 * MB);   // aliases kb (dead)
  float*          pp  = (float*)(ws + 34 * MB);            // aliases kb tail (dead)

  k_cvt_x<<<(NB * T_ * DM) / 256, 256, 0, stream>>>(x, xb);

  dim3 tb(32, 8);
  k_transpose<<<dim3(HD / 32, DM / 32, NHEADS), tb, 0, stream>>>(Wq, wqT, DM, HD);
  k_transpose<<<dim3(HD / 32, DM / 32, NHEADS), tb, 0, stream>>>(Wk, wkT, DM, HD);
  k_transpose<<<dim3(HD / 32, DM / 32, NHEADS), tb, 0, stream>>>(Wv, wvT, DM, HD);

  k_kvgemm<<<dim3(16, 128, 2), 256, 0, stream>>>(
      xb, wkT, wvT, cosx, sinx, cosy, siny, kb, vtb);

  k_attn_fq<<<dim3(T_ / 128, NB * NHEADS), 512, 0, stream>>>(
      xb, wqT, kb, vtb, cosx, sinx, cosy, siny, ao);

  k_transpose<<<dim3(DM / 32, (NHEADS * HD) / 32, 1), tb, 0, stream>>>(Wp, wpT, NHEADS * HD, DM);

  k_proj_sk<<<dim3(16, 4, 8), 256, 0, stream>>>(ao, wpT, pp);
  k_pred<<<(2048 * 512 / 4) / 256, 256, 0, stream>>>(pp, bp, out);
}